// Round 2
// baseline (2835.890 us; speedup 1.0000x reference)
//
#include <hip/hip_runtime.h>
#include <hip/hip_bf16.h>
#include <math.h>

// Problem constants
#define B_ 32
#define C_ 512
#define G_ 32
#define CPG_ 16          // channels per group
#define N_ 1024          // H*W
#define OC3_ 1536        // 3*C
#define EPS_ 1e-5f

// ---------------------------------------------------------------------------
// Kernel 1: GroupNorm statistics. One block per (b,g). Group channels are
// contiguous: 16 channels x 1024 spatial = 16384 floats = 4096 float4.
// Runs once for ALL batches (stats = 2048 floats only).
// ---------------------------------------------------------------------------
__global__ __launch_bounds__(256) void gn_stats_kernel(
    const float* __restrict__ x, float* __restrict__ stats)
{
    int bg = blockIdx.x;                      // b*32 + g
    const float4* xv = (const float4*)(x + (size_t)bg * CPG_ * N_);
    float s = 0.f, ss = 0.f;
    for (int i = threadIdx.x; i < 4096; i += 256) {
        float4 v = xv[i];
        s  += v.x + v.y + v.z + v.w;
        ss += v.x*v.x + v.y*v.y + v.z*v.z + v.w*v.w;
    }
    __shared__ float r1[256], r2[256];
    r1[threadIdx.x] = s; r2[threadIdx.x] = ss;
    __syncthreads();
    for (int off = 128; off > 0; off >>= 1) {
        if (threadIdx.x < off) {
            r1[threadIdx.x] += r1[threadIdx.x + off];
            r2[threadIdx.x] += r2[threadIdx.x + off];
        }
        __syncthreads();
    }
    if (threadIdx.x == 0) {
        float mean = r1[0] * (1.f / 16384.f);
        float var  = r2[0] * (1.f / 16384.f) - mean * mean;
        stats[bg * 2 + 0] = mean;
        stats[bg * 2 + 1] = rsqrtf(var + EPS_);
    }
}

// ---------------------------------------------------------------------------
// Kernel 2: QKV GEMM with fused GroupNorm normalize on the B-operand load.
// qkv[bz,o,n] = sum_c W[o,c] * hhat(b0+bz,c,n) + bias[o]
// Tiles: BM=64 (o), BN=64 (n), BK=16 (c). 256 threads, 4x4 micro-tile.
// ---------------------------------------------------------------------------
__global__ __launch_bounds__(256) void qkv_gemm_kernel(
    const float* __restrict__ x, const float* __restrict__ stats,
    const float* __restrict__ nw, const float* __restrict__ nb,
    const float* __restrict__ w, const float* __restrict__ bias,
    float* __restrict__ qkv, int b0)
{
    int bz = blockIdx.z;
    int b  = b0 + bz;
    int om = blockIdx.x * 64;    // output-channel tile (0..1536)
    int nn = blockIdx.y * 64;    // spatial tile (0..1024)
    const float* xb = x + (size_t)b * C_ * N_;
    const float* st = stats + b * 2 * G_;

    __shared__ float As[16][65];   // As[c][o]
    __shared__ float Bs[16][65];   // Bs[c][n]

    int tid = threadIdx.x;
    int tm = tid >> 4, tn = tid & 15;
    float acc[4][4];
    #pragma unroll
    for (int i = 0; i < 4; ++i)
        #pragma unroll
        for (int j = 0; j < 4; ++j) acc[i][j] = 0.f;

    int ca = tid & 15, oa = tid >> 4;        // A-tile load coords
    int nl = tid & 63, cb0 = tid >> 6;       // B-tile load coords

    for (int k0 = 0; k0 < C_; k0 += 16) {
        #pragma unroll
        for (int r = 0; r < 4; ++r) {
            int o = oa + r * 16;
            As[ca][o] = w[(size_t)(om + o) * C_ + k0 + ca];
        }
        #pragma unroll
        for (int r = 0; r < 4; ++r) {
            int c  = cb0 + r * 4;
            int cg = k0 + c;
            float xv = xb[(size_t)cg * N_ + nn + nl];
            int g = cg >> 4;
            float mean = st[g * 2], rstd = st[g * 2 + 1];
            Bs[c][nl] = (xv - mean) * rstd * nw[cg] + nb[cg];
        }
        __syncthreads();
        #pragma unroll
        for (int kk = 0; kk < 16; ++kk) {
            float a[4], bb[4];
            #pragma unroll
            for (int i = 0; i < 4; ++i) a[i]  = As[kk][tm * 4 + i];
            #pragma unroll
            for (int j = 0; j < 4; ++j) bb[j] = Bs[kk][tn * 4 + j];
            #pragma unroll
            for (int i = 0; i < 4; ++i)
                #pragma unroll
                for (int j = 0; j < 4; ++j) acc[i][j] += a[i] * bb[j];
        }
        __syncthreads();
    }
    #pragma unroll
    for (int i = 0; i < 4; ++i) {
        int o = om + tm * 4 + i;
        float bo = bias[o];
        #pragma unroll
        for (int j = 0; j < 4; ++j)
            qkv[((size_t)bz * OC3_ + o) * N_ + nn + tn * 4 + j] = acc[i][j] + bo;
    }
}

// ---------------------------------------------------------------------------
// Kernel 3: scores[bz,n,m] = scale * sum_c q[bz,c,n] * k[bz,c,m]
// ---------------------------------------------------------------------------
__global__ __launch_bounds__(256) void scores_kernel(
    const float* __restrict__ qkv, float* __restrict__ scores)
{
    int bz = blockIdx.z;
    int nt = blockIdx.x * 64;    // n tile
    int mt = blockIdx.y * 64;    // m tile
    const float* q = qkv + (size_t)bz * OC3_ * N_;
    const float* k = q + (size_t)C_ * N_;
    const float scale = 0.044194173824159216f;  // 512^-0.5

    __shared__ float As[16][65];   // As[c][n]
    __shared__ float Bs[16][65];   // Bs[c][m]

    int tid = threadIdx.x;
    int tm = tid >> 4, tn = tid & 15;
    float acc[4][4];
    #pragma unroll
    for (int i = 0; i < 4; ++i)
        #pragma unroll
        for (int j = 0; j < 4; ++j) acc[i][j] = 0.f;

    int nl = tid & 63, c0 = tid >> 6;

    for (int k0 = 0; k0 < C_; k0 += 16) {
        #pragma unroll
        for (int r = 0; r < 4; ++r) {
            int c = c0 + r * 4;
            As[c][nl] = q[(size_t)(k0 + c) * N_ + nt + nl];
            Bs[c][nl] = k[(size_t)(k0 + c) * N_ + mt + nl];
        }
        __syncthreads();
        #pragma unroll
        for (int kk = 0; kk < 16; ++kk) {
            float a[4], bb[4];
            #pragma unroll
            for (int i = 0; i < 4; ++i) a[i]  = As[kk][tm * 4 + i];
            #pragma unroll
            for (int j = 0; j < 4; ++j) bb[j] = Bs[kk][tn * 4 + j];
            #pragma unroll
            for (int i = 0; i < 4; ++i)
                #pragma unroll
                for (int j = 0; j < 4; ++j) acc[i][j] += a[i] * bb[j];
        }
        __syncthreads();
    }
    #pragma unroll
    for (int i = 0; i < 4; ++i) {
        int n = nt + tm * 4 + i;
        #pragma unroll
        for (int j = 0; j < 4; ++j)
            scores[((size_t)bz * N_ + n) * N_ + mt + tn * 4 + j] = acc[i][j] * scale;
    }
}

// ---------------------------------------------------------------------------
// Kernel 4: row softmax over m. One block per row within the chunk.
// ---------------------------------------------------------------------------
__global__ __launch_bounds__(256) void softmax_kernel(float* __restrict__ attn)
{
    size_t row = blockIdx.x;
    float4* p = (float4*)(attn + row * N_);
    int tid = threadIdx.x;
    float4 v = p[tid];

    __shared__ float red[256];
    float m = fmaxf(fmaxf(v.x, v.y), fmaxf(v.z, v.w));
    red[tid] = m; __syncthreads();
    for (int off = 128; off > 0; off >>= 1) {
        if (tid < off) red[tid] = fmaxf(red[tid], red[tid + off]);
        __syncthreads();
    }
    m = red[0]; __syncthreads();

    v.x = expf(v.x - m); v.y = expf(v.y - m);
    v.z = expf(v.z - m); v.w = expf(v.w - m);
    red[tid] = v.x + v.y + v.z + v.w; __syncthreads();
    for (int off = 128; off > 0; off >>= 1) {
        if (tid < off) red[tid] += red[tid + off];
        __syncthreads();
    }
    float inv = 1.f / red[0];
    v.x *= inv; v.y *= inv; v.z *= inv; v.w *= inv;
    p[tid] = v;
}

// ---------------------------------------------------------------------------
// Kernel 5: hout[bz,c,n] = sum_m v[bz,c,m] * attn[bz,n,m]
// K-dim = m (contiguous in both operands) -> transpose tiles on LDS store.
// ---------------------------------------------------------------------------
__global__ __launch_bounds__(256) void hout_gemm_kernel(
    const float* __restrict__ qkv, const float* __restrict__ attn,
    float* __restrict__ hout)
{
    int bz = blockIdx.z;
    int cm = blockIdx.x * 64;    // c tile (0..512)
    int nn = blockIdx.y * 64;    // n tile (0..1024)
    const float* v = qkv + (size_t)bz * OC3_ * N_ + (size_t)2 * C_ * N_;
    const float* at = attn + (size_t)bz * N_ * N_;

    __shared__ float As[16][65];   // As[m][c]
    __shared__ float Bs[16][65];   // Bs[m][n]

    int tid = threadIdx.x;
    int tm = tid >> 4, tn = tid & 15;
    float acc[4][4];
    #pragma unroll
    for (int i = 0; i < 4; ++i)
        #pragma unroll
        for (int j = 0; j < 4; ++j) acc[i][j] = 0.f;

    int ml = tid & 15, rl0 = tid >> 4;   // (m within tile, row group)

    for (int k0 = 0; k0 < N_; k0 += 16) {
        #pragma unroll
        for (int r = 0; r < 4; ++r) {
            int c = rl0 + r * 16;
            As[ml][c] = v[(size_t)(cm + c) * N_ + k0 + ml];
            Bs[ml][c] = at[(size_t)(nn + c) * N_ + k0 + ml];
        }
        __syncthreads();
        #pragma unroll
        for (int kk = 0; kk < 16; ++kk) {
            float a[4], bb[4];
            #pragma unroll
            for (int i = 0; i < 4; ++i) a[i]  = As[kk][tm * 4 + i];
            #pragma unroll
            for (int j = 0; j < 4; ++j) bb[j] = Bs[kk][tn * 4 + j];
            #pragma unroll
            for (int i = 0; i < 4; ++i)
                #pragma unroll
                for (int j = 0; j < 4; ++j) acc[i][j] += a[i] * bb[j];
        }
        __syncthreads();
    }
    #pragma unroll
    for (int i = 0; i < 4; ++i) {
        int c = cm + tm * 4 + i;
        #pragma unroll
        for (int j = 0; j < 4; ++j)
            hout[((size_t)bz * C_ + c) * N_ + nn + tn * 4 + j] = acc[i][j];
    }
}

// ---------------------------------------------------------------------------
// Kernel 6: out[b,o,n] = x[b,o,n] + proj_b[o] + sum_c pw[o,c] * hout[bz,c,n]
// ---------------------------------------------------------------------------
__global__ __launch_bounds__(256) void proj_gemm_kernel(
    const float* __restrict__ hout, const float* __restrict__ pw,
    const float* __restrict__ pb, const float* __restrict__ x,
    float* __restrict__ out, int b0)
{
    int bz = blockIdx.z;
    int b  = b0 + bz;
    int om = blockIdx.x * 64;
    int nn = blockIdx.y * 64;
    const float* hb = hout + (size_t)bz * C_ * N_;
    const float* xb = x + (size_t)b * C_ * N_;
    float* ob = out + (size_t)b * C_ * N_;

    __shared__ float As[16][65];   // As[c][o]
    __shared__ float Bs[16][65];   // Bs[c][n]

    int tid = threadIdx.x;
    int tm = tid >> 4, tn = tid & 15;
    float acc[4][4];
    #pragma unroll
    for (int i = 0; i < 4; ++i)
        #pragma unroll
        for (int j = 0; j < 4; ++j) acc[i][j] = 0.f;

    int ca = tid & 15, oa = tid >> 4;
    int nl = tid & 63, cb0 = tid >> 6;

    for (int k0 = 0; k0 < C_; k0 += 16) {
        #pragma unroll
        for (int r = 0; r < 4; ++r) {
            int o = oa + r * 16;
            As[ca][o] = pw[(size_t)(om + o) * C_ + k0 + ca];
        }
        #pragma unroll
        for (int r = 0; r < 4; ++r) {
            int c = cb0 + r * 4;
            Bs[c][nl] = hb[(size_t)(k0 + c) * N_ + nn + nl];
        }
        __syncthreads();
        #pragma unroll
        for (int kk = 0; kk < 16; ++kk) {
            float a[4], bb[4];
            #pragma unroll
            for (int i = 0; i < 4; ++i) a[i]  = As[kk][tm * 4 + i];
            #pragma unroll
            for (int j = 0; j < 4; ++j) bb[j] = Bs[kk][tn * 4 + j];
            #pragma unroll
            for (int i = 0; i < 4; ++i)
                #pragma unroll
                for (int j = 0; j < 4; ++j) acc[i][j] += a[i] * bb[j];
        }
        __syncthreads();
    }
    #pragma unroll
    for (int i = 0; i < 4; ++i) {
        int o = om + tm * 4 + i;
        float bo = pb[o];
        #pragma unroll
        for (int j = 0; j < 4; ++j) {
            size_t idx = ((size_t)o) * N_ + nn + tn * 4 + j;
            ob[idx] = xb[idx] + acc[i][j] + bo;
        }
    }
}

// ---------------------------------------------------------------------------
extern "C" void kernel_launch(void* const* d_in, const int* in_sizes, int n_in,
                              void* d_out, int out_size, void* d_ws, size_t ws_size,
                              hipStream_t stream) {
    const float* x      = (const float*)d_in[0];
    const float* norm_w = (const float*)d_in[1];
    const float* norm_b = (const float*)d_in[2];
    const float* qkv_w  = (const float*)d_in[3];
    const float* qkv_b  = (const float*)d_in[4];
    const float* proj_w = (const float*)d_in[5];
    const float* proj_b = (const float*)d_in[6];
    float* out = (float*)d_out;

    // Adaptive workspace: per-batch needs qkv(1536*1024) + attn(1024*1024)
    // + hout(512*1024) = 3,145,728 floats = 12.58 MB. Chunk the batch dim
    // so we never exceed ws_size (Round-0 crash root cause: 403 MB
    // unconditional layout overran d_ws).
    const size_t per_batch_fl = (size_t)(OC3_ + N_ + C_) * N_;   // 3,145,728
    float* ws    = (float*)d_ws;
    float* stats = ws;                               // 2048 floats
    float* base  = ws + 2048;

    size_t avail_fl = ws_size / 4 > 2048 ? ws_size / 4 - 2048 : 0;
    int chunk = (int)(avail_fl / per_batch_fl);
    if (chunk < 1) chunk = 1;          // assume >= ~12.6 MB scratch
    if (chunk > B_) chunk = B_;

    gn_stats_kernel<<<dim3(B_ * G_), dim3(256), 0, stream>>>(x, stats);

    for (int b0 = 0; b0 < B_; b0 += chunk) {
        int nb = B_ - b0 < chunk ? B_ - b0 : chunk;
        float* qkv  = base;
        float* attn = qkv + (size_t)nb * OC3_ * N_;
        float* hout = attn + (size_t)nb * N_ * N_;

        qkv_gemm_kernel<<<dim3(OC3_ / 64, N_ / 64, nb), dim3(256), 0, stream>>>(
            x, stats, norm_w, norm_b, qkv_w, qkv_b, qkv, b0);

        scores_kernel<<<dim3(N_ / 64, N_ / 64, nb), dim3(256), 0, stream>>>(qkv, attn);

        softmax_kernel<<<dim3(nb * N_), dim3(256), 0, stream>>>(attn);

        hout_gemm_kernel<<<dim3(C_ / 64, N_ / 64, nb), dim3(256), 0, stream>>>(
            qkv, attn, hout);

        proj_gemm_kernel<<<dim3(C_ / 64, N_ / 64, nb), dim3(256), 0, stream>>>(
            hout, proj_w, proj_b, x, out, b0);
    }
}

// Round 3
// 872.882 us; speedup vs baseline: 3.2489x; 3.2489x over previous
//
#include <hip/hip_runtime.h>
#include <math.h>

// Problem constants
#define B_ 32
#define C_ 512
#define G_ 32
#define N_ 1024          // H*W
#define OC3_ 1536        // 3*C
#define EPS_ 1e-5f
#define RS 40            // LDS row stride in shorts (80 B = 16B-aligned; frag
                         // ds_read_b128 lands 2-way on banks = free per m136)

typedef __attribute__((ext_vector_type(8))) short short8;
typedef __attribute__((ext_vector_type(4))) float f32x4;

// fp32 -> bf16 RNE (bit trick; inputs are finite)
__device__ inline unsigned short f2bf(float f) {
    unsigned u = __builtin_bit_cast(unsigned, f);
    u += 0x7fffu + ((u >> 16) & 1u);
    return (unsigned short)(u >> 16);
}
__device__ inline unsigned pack2(float lo, float hi) {
    return (unsigned)f2bf(lo) | ((unsigned)f2bf(hi) << 16);
}

// ---------------------------------------------------------------------------
// Kernel 1: GroupNorm statistics. One block per (b,g): 16 ch x 1024 = 16384 f.
// ---------------------------------------------------------------------------
__global__ __launch_bounds__(256) void gn_stats_kernel(
    const float* __restrict__ x, float* __restrict__ stats)
{
    int bg = blockIdx.x;
    const float4* xv = (const float4*)(x + (size_t)bg * 16 * N_);
    float s = 0.f, ss = 0.f;
    for (int i = threadIdx.x; i < 4096; i += 256) {
        float4 v = xv[i];
        s  += v.x + v.y + v.z + v.w;
        ss += v.x*v.x + v.y*v.y + v.z*v.z + v.w*v.w;
    }
    __shared__ float r1[256], r2[256];
    r1[threadIdx.x] = s; r2[threadIdx.x] = ss;
    __syncthreads();
    for (int off = 128; off > 0; off >>= 1) {
        if (threadIdx.x < off) {
            r1[threadIdx.x] += r1[threadIdx.x + off];
            r2[threadIdx.x] += r2[threadIdx.x + off];
        }
        __syncthreads();
    }
    if (threadIdx.x == 0) {
        float mean = r1[0] * (1.f / 16384.f);
        float var  = r2[0] * (1.f / 16384.f) - mean * mean;
        stats[bg * 2 + 0] = mean;
        stats[bg * 2 + 1] = rsqrtf(var + EPS_);
    }
}

// ---------------------------------------------------------------------------
// Kernel 2: QKV GEMM (bf16 MFMA), GN fused into B staging.
// D[o][n] = sum_c W[o][c] * hhat[c][n];  A=W (k-contig), B=hhat (transposed
// into Bs[n][c] during staging). Output qkv as bf16.
// ---------------------------------------------------------------------------
__global__ __launch_bounds__(256) void qkv_gemm_kernel(
    const float* __restrict__ x, const float* __restrict__ stats,
    const float* __restrict__ nrm_w, const float* __restrict__ nrm_b,
    const float* __restrict__ w, const float* __restrict__ bias,
    unsigned short* __restrict__ qkv, int b0)
{
    int bz = blockIdx.z, b = b0 + bz;
    int om = blockIdx.x * 64, nn = blockIdx.y * 64;
    const float* xb = x + (size_t)b * C_ * N_;
    const float* st = stats + b * 2 * G_;

    __shared__ __align__(16) short As[64 * RS];  // [o][c]
    __shared__ __align__(16) short Bs[64 * RS];  // [n][c]

    int tid = threadIdx.x;
    int wv = tid >> 6, lane = tid & 63;
    int lm = lane & 15, q = lane >> 4;

    f32x4 acc[4];
    #pragma unroll
    for (int t = 0; t < 4; ++t) acc[t] = (f32x4)(0.f);

    int ar = tid >> 2, ac = (tid & 3) * 8;

    for (int k0 = 0; k0 < C_; k0 += 32) {
        // A tile: W[om+ar][k0+ac..+7], coalesced float4 pairs -> b128 write
        {
            const float* p = &w[(size_t)(om + ar) * C_ + k0 + ac];
            float4 f0 = *(const float4*)p;
            float4 f1 = *(const float4*)(p + 4);
            short8 s;
            s[0]=(short)f2bf(f0.x); s[1]=(short)f2bf(f0.y);
            s[2]=(short)f2bf(f0.z); s[3]=(short)f2bf(f0.w);
            s[4]=(short)f2bf(f1.x); s[5]=(short)f2bf(f1.y);
            s[6]=(short)f2bf(f1.z); s[7]=(short)f2bf(f1.w);
            *(short8*)&As[ar * RS + ac] = s;
        }
        // B tile: transpose hhat[c][n] -> Bs[n][c]; c-pairs packed in dwords.
        #pragma unroll
        for (int p = 0; p < 2; ++p) {
            int s_ = p * 256 + tid;            // 0..511
            int np = s_ & 31, cp = s_ >> 5;    // n = 2*np, c = 2*cp
            int c0 = k0 + cp * 2;
            int n0 = nn + np * 2;
            float2 r0 = *(const float2*)&xb[(size_t)c0 * N_ + n0];
            float2 r1 = *(const float2*)&xb[(size_t)(c0 + 1) * N_ + n0];
            int g = c0 >> 4;
            float mean = st[g*2], rstd = st[g*2+1];
            float w0 = nrm_w[c0]   * rstd, bb0 = nrm_b[c0]   - mean * w0;
            float w1 = nrm_w[c0+1] * rstd, bb1 = nrm_b[c0+1] - mean * w1;
            *(unsigned*)&Bs[(np*2)   * RS + cp*2] = pack2(r0.x*w0+bb0, r1.x*w1+bb1);
            *(unsigned*)&Bs[(np*2+1) * RS + cp*2] = pack2(r0.y*w0+bb0, r1.y*w1+bb1);
        }
        __syncthreads();
        short8 a = *(short8*)&As[(wv*16 + lm) * RS + q*8];
        #pragma unroll
        for (int t = 0; t < 4; ++t) {
            short8 bb = *(short8*)&Bs[(t*16 + lm) * RS + q*8];
            acc[t] = __builtin_amdgcn_mfma_f32_16x16x32_bf16(a, bb, acc[t], 0, 0, 0);
        }
        __syncthreads();
    }
    #pragma unroll
    for (int t = 0; t < 4; ++t) {
        int n = nn + t*16 + lm;
        #pragma unroll
        for (int r = 0; r < 4; ++r) {
            int o = om + wv*16 + q*4 + r;       // C/D: row=q*4+r, col=lm
            qkv[((size_t)bz * OC3_ + o) * N_ + n] = f2bf(acc[t][r] + bias[o]);
        }
    }
}

// ---------------------------------------------------------------------------
// Kernel 3: scores[n][m] = scale * sum_c q[c][n] * k[c][m]  (bf16 MFMA)
// Both operands transposed into [row][c] LDS tiles from bf16 qkv.
// ---------------------------------------------------------------------------
__global__ __launch_bounds__(256) void scores_kernel(
    const unsigned short* __restrict__ qkv, float* __restrict__ scores)
{
    int bz = blockIdx.z;
    int nt = blockIdx.x * 64, mt = blockIdx.y * 64;
    const unsigned short* qp = qkv + (size_t)bz * OC3_ * N_;
    const unsigned short* kp = qp + (size_t)C_ * N_;
    const float scale = 0.044194173824159216f;

    __shared__ __align__(16) short As[64 * RS];  // [n][c]
    __shared__ __align__(16) short Bs[64 * RS];  // [m][c]

    int tid = threadIdx.x;
    int wv = tid >> 6, lane = tid & 63;
    int lm = lane & 15, q = lane >> 4;

    f32x4 acc[4];
    #pragma unroll
    for (int t = 0; t < 4; ++t) acc[t] = (f32x4)(0.f);

    for (int k0 = 0; k0 < C_; k0 += 32) {
        #pragma unroll
        for (int p = 0; p < 2; ++p) {
            int s_ = p * 256 + tid;
            int np = s_ & 31, cp = s_ >> 5;
            int c0 = k0 + cp * 2;
            // A from q
            unsigned v0 = *(const unsigned*)&qp[(size_t)c0 * N_ + nt + np*2];
            unsigned v1 = *(const unsigned*)&qp[(size_t)(c0+1) * N_ + nt + np*2];
            *(unsigned*)&As[(np*2)   * RS + cp*2] = (v0 & 0xffffu) | (v1 << 16);
            *(unsigned*)&As[(np*2+1) * RS + cp*2] = (v0 >> 16) | (v1 & 0xffff0000u);
            // B from k
            unsigned u0 = *(const unsigned*)&kp[(size_t)c0 * N_ + mt + np*2];
            unsigned u1 = *(const unsigned*)&kp[(size_t)(c0+1) * N_ + mt + np*2];
            *(unsigned*)&Bs[(np*2)   * RS + cp*2] = (u0 & 0xffffu) | (u1 << 16);
            *(unsigned*)&Bs[(np*2+1) * RS + cp*2] = (u0 >> 16) | (u1 & 0xffff0000u);
        }
        __syncthreads();
        short8 a = *(short8*)&As[(wv*16 + lm) * RS + q*8];
        #pragma unroll
        for (int t = 0; t < 4; ++t) {
            short8 bb = *(short8*)&Bs[(t*16 + lm) * RS + q*8];
            acc[t] = __builtin_amdgcn_mfma_f32_16x16x32_bf16(a, bb, acc[t], 0, 0, 0);
        }
        __syncthreads();
    }
    #pragma unroll
    for (int t = 0; t < 4; ++t) {
        int m = mt + t*16 + lm;
        #pragma unroll
        for (int r = 0; r < 4; ++r) {
            int n = nt + wv*16 + q*4 + r;
            scores[((size_t)bz * N_ + n) * N_ + m] = acc[t][r] * scale;
        }
    }
}

// ---------------------------------------------------------------------------
// Kernel 4: row softmax over m (fp32 in-place).
// ---------------------------------------------------------------------------
__global__ __launch_bounds__(256) void softmax_kernel(float* __restrict__ attn)
{
    size_t row = blockIdx.x;
    float4* p = (float4*)(attn + row * N_);
    int tid = threadIdx.x;
    float4 v = p[tid];

    __shared__ float red[256];
    float m = fmaxf(fmaxf(v.x, v.y), fmaxf(v.z, v.w));
    red[tid] = m; __syncthreads();
    for (int off = 128; off > 0; off >>= 1) {
        if (tid < off) red[tid] = fmaxf(red[tid], red[tid + off]);
        __syncthreads();
    }
    m = red[0]; __syncthreads();

    v.x = expf(v.x - m); v.y = expf(v.y - m);
    v.z = expf(v.z - m); v.w = expf(v.w - m);
    red[tid] = v.x + v.y + v.z + v.w; __syncthreads();
    for (int off = 128; off > 0; off >>= 1) {
        if (tid < off) red[tid] += red[tid + off];
        __syncthreads();
    }
    float inv = 1.f / red[0];
    v.x *= inv; v.y *= inv; v.z *= inv; v.w *= inv;
    p[tid] = v;
}

// ---------------------------------------------------------------------------
// Kernel 5: hout[c][n] = sum_m v[c][m] * attn[n][m]  (bf16 MFMA, K = m)
// Both operands k-contiguous in global -> direct b128 staging, no transpose.
// Output hout as bf16.
// ---------------------------------------------------------------------------
__global__ __launch_bounds__(256) void hout_gemm_kernel(
    const unsigned short* __restrict__ qkv, const float* __restrict__ attn,
    unsigned short* __restrict__ hout)
{
    int bz = blockIdx.z;
    int cm = blockIdx.x * 64, nn = blockIdx.y * 64;
    const unsigned short* vp = qkv + (size_t)bz * OC3_ * N_ + (size_t)2 * C_ * N_;
    const float* at = attn + (size_t)bz * N_ * N_;

    __shared__ __align__(16) short As[64 * RS];  // [c][m]
    __shared__ __align__(16) short Bs[64 * RS];  // [n][m]

    int tid = threadIdx.x;
    int wv = tid >> 6, lane = tid & 63;
    int lm = lane & 15, q = lane >> 4;

    f32x4 acc[4];
    #pragma unroll
    for (int t = 0; t < 4; ++t) acc[t] = (f32x4)(0.f);

    int r_ = tid >> 2, mg = (tid & 3) * 8;

    for (int k0 = 0; k0 < N_; k0 += 32) {
        // A: v[cm+r_][k0+mg..+7] (bf16, contiguous)
        *(short8*)&As[r_ * RS + mg] =
            *(const short8*)&vp[(size_t)(cm + r_) * N_ + k0 + mg];
        // B: attn[nn+r_][k0+mg..+7] fp32 -> bf16
        {
            const float* p = &at[(size_t)(nn + r_) * N_ + k0 + mg];
            float4 f0 = *(const float4*)p;
            float4 f1 = *(const float4*)(p + 4);
            short8 s;
            s[0]=(short)f2bf(f0.x); s[1]=(short)f2bf(f0.y);
            s[2]=(short)f2bf(f0.z); s[3]=(short)f2bf(f0.w);
            s[4]=(short)f2bf(f1.x); s[5]=(short)f2bf(f1.y);
            s[6]=(short)f2bf(f1.z); s[7]=(short)f2bf(f1.w);
            *(short8*)&Bs[r_ * RS + mg] = s;
        }
        __syncthreads();
        short8 a = *(short8*)&As[(wv*16 + lm) * RS + q*8];
        #pragma unroll
        for (int t = 0; t < 4; ++t) {
            short8 bb = *(short8*)&Bs[(t*16 + lm) * RS + q*8];
            acc[t] = __builtin_amdgcn_mfma_f32_16x16x32_bf16(a, bb, acc[t], 0, 0, 0);
        }
        __syncthreads();
    }
    #pragma unroll
    for (int t = 0; t < 4; ++t) {
        int n = nn + t*16 + lm;
        #pragma unroll
        for (int r = 0; r < 4; ++r) {
            int c = cm + wv*16 + q*4 + r;
            hout[((size_t)bz * C_ + c) * N_ + n] = f2bf(acc[t][r]);
        }
    }
}

// ---------------------------------------------------------------------------
// Kernel 6: out[o][n] = x + proj_b[o] + sum_c pw[o][c] * hout[c][n]
// A = pw (k-contig fp32), B = hout bf16 transposed into Bs[n][c].
// ---------------------------------------------------------------------------
__global__ __launch_bounds__(256) void proj_gemm_kernel(
    const unsigned short* __restrict__ hout, const float* __restrict__ pw,
    const float* __restrict__ pb, const float* __restrict__ x,
    float* __restrict__ out, int b0)
{
    int bz = blockIdx.z, b = b0 + bz;
    int om = blockIdx.x * 64, nn = blockIdx.y * 64;
    const unsigned short* hb = hout + (size_t)bz * C_ * N_;
    const float* xb = x + (size_t)b * C_ * N_;
    float* ob = out + (size_t)b * C_ * N_;

    __shared__ __align__(16) short As[64 * RS];  // [o][c]
    __shared__ __align__(16) short Bs[64 * RS];  // [n][c]

    int tid = threadIdx.x;
    int wv = tid >> 6, lane = tid & 63;
    int lm = lane & 15, q = lane >> 4;

    f32x4 acc[4];
    #pragma unroll
    for (int t = 0; t < 4; ++t) acc[t] = (f32x4)(0.f);

    int ar = tid >> 2, ac = (tid & 3) * 8;

    for (int k0 = 0; k0 < C_; k0 += 32) {
        {
            const float* p = &pw[(size_t)(om + ar) * C_ + k0 + ac];
            float4 f0 = *(const float4*)p;
            float4 f1 = *(const float4*)(p + 4);
            short8 s;
            s[0]=(short)f2bf(f0.x); s[1]=(short)f2bf(f0.y);
            s[2]=(short)f2bf(f0.z); s[3]=(short)f2bf(f0.w);
            s[4]=(short)f2bf(f1.x); s[5]=(short)f2bf(f1.y);
            s[6]=(short)f2bf(f1.z); s[7]=(short)f2bf(f1.w);
            *(short8*)&As[ar * RS + ac] = s;
        }
        #pragma unroll
        for (int p = 0; p < 2; ++p) {
            int s_ = p * 256 + tid;
            int np = s_ & 31, cp = s_ >> 5;
            int c0 = k0 + cp * 2;
            unsigned v0 = *(const unsigned*)&hb[(size_t)c0 * N_ + nn + np*2];
            unsigned v1 = *(const unsigned*)&hb[(size_t)(c0+1) * N_ + nn + np*2];
            *(unsigned*)&Bs[(np*2)   * RS + cp*2] = (v0 & 0xffffu) | (v1 << 16);
            *(unsigned*)&Bs[(np*2+1) * RS + cp*2] = (v0 >> 16) | (v1 & 0xffff0000u);
        }
        __syncthreads();
        short8 a = *(short8*)&As[(wv*16 + lm) * RS + q*8];
        #pragma unroll
        for (int t = 0; t < 4; ++t) {
            short8 bb = *(short8*)&Bs[(t*16 + lm) * RS + q*8];
            acc[t] = __builtin_amdgcn_mfma_f32_16x16x32_bf16(a, bb, acc[t], 0, 0, 0);
        }
        __syncthreads();
    }
    #pragma unroll
    for (int t = 0; t < 4; ++t) {
        int n = nn + t*16 + lm;
        #pragma unroll
        for (int r = 0; r < 4; ++r) {
            int o = om + wv*16 + q*4 + r;
            size_t idx = (size_t)o * N_ + n;
            ob[idx] = xb[idx] + acc[t][r] + pb[o];
        }
    }
}

// ---------------------------------------------------------------------------
extern "C" void kernel_launch(void* const* d_in, const int* in_sizes, int n_in,
                              void* d_out, int out_size, void* d_ws, size_t ws_size,
                              hipStream_t stream) {
    const float* x      = (const float*)d_in[0];
    const float* norm_w = (const float*)d_in[1];
    const float* norm_b = (const float*)d_in[2];
    const float* qkv_w  = (const float*)d_in[3];
    const float* qkv_b  = (const float*)d_in[4];
    const float* proj_w = (const float*)d_in[5];
    const float* proj_b = (const float*)d_in[6];
    float* out = (float*)d_out;

    // Per-batch workspace: qkv bf16 (3 MB) + attn fp32 (4 MB) + hout bf16 (1 MB)
    const size_t per_batch = (size_t)OC3_ * N_ * 2 + (size_t)N_ * N_ * 4
                           + (size_t)C_ * N_ * 2;   // 8 MB
    char* ws = (char*)d_ws;
    float* stats = (float*)ws;                       // 8 KB
    char*  base  = ws + 8192;

    size_t avail = ws_size > 8192 ? ws_size - 8192 : 0;
    int chunk = (int)(avail / per_batch);
    if (chunk < 1) chunk = 1;
    if (chunk > B_) chunk = B_;

    gn_stats_kernel<<<dim3(B_ * G_), dim3(256), 0, stream>>>(x, stats);

    for (int b0 = 0; b0 < B_; b0 += chunk) {
        int nb = B_ - b0 < chunk ? B_ - b0 : chunk;
        unsigned short* qkv  = (unsigned short*)base;
        float* attn = (float*)(base + (size_t)nb * OC3_ * N_ * 2);
        unsigned short* hout = (unsigned short*)((char*)attn + (size_t)nb * N_ * N_ * 4);

        qkv_gemm_kernel<<<dim3(OC3_/64, N_/64, nb), dim3(256), 0, stream>>>(
            x, stats, norm_w, norm_b, qkv_w, qkv_b, qkv, b0);

        scores_kernel<<<dim3(N_/64, N_/64, nb), dim3(256), 0, stream>>>(qkv, attn);

        softmax_kernel<<<dim3(nb * N_), dim3(256), 0, stream>>>(attn);

        hout_gemm_kernel<<<dim3(C_/64, N_/64, nb), dim3(256), 0, stream>>>(
            qkv, attn, hout);

        proj_gemm_kernel<<<dim3(C_/64, N_/64, nb), dim3(256), 0, stream>>>(
            hout, proj_w, proj_b, x, out, b0);
    }
}

// Round 5
// 573.572 us; speedup vs baseline: 4.9443x; 1.5218x over previous
//
#include <hip/hip_runtime.h>
#include <math.h>

// Problem constants
#define B_ 32
#define C_ 512
#define G_ 32
#define N_ 1024          // H*W
#define OC3_ 1536        // 3*C
#define EPS_ 1e-5f
#define LRS 40           // LDS row stride in shorts (80 B): frag ds_read_b128
                         // lands 2-way on banks = free (m136)

typedef __attribute__((ext_vector_type(8))) short short8;
typedef __attribute__((ext_vector_type(4))) float f32x4;

// fp32 -> bf16 RNE
__device__ inline unsigned short f2bf(float f) {
    unsigned u = __builtin_bit_cast(unsigned, f);
    u += 0x7fffu + ((u >> 16) & 1u);
    return (unsigned short)(u >> 16);
}
__device__ inline unsigned pack2(float lo, float hi) {
    return (unsigned)f2bf(lo) | ((unsigned)f2bf(hi) << 16);
}

// ---------------------------------------------------------------------------
// GroupNorm statistics. One block per (b,g): 16 ch x 1024 = 16384 floats.
// ---------------------------------------------------------------------------
__global__ __launch_bounds__(256) void gn_stats_kernel(
    const float* __restrict__ x, float* __restrict__ stats)
{
    int bg = blockIdx.x;
    const float4* xv = (const float4*)(x + (size_t)bg * 16 * N_);
    float s = 0.f, ss = 0.f;
    for (int i = threadIdx.x; i < 4096; i += 256) {
        float4 v = xv[i];
        s  += v.x + v.y + v.z + v.w;
        ss += v.x*v.x + v.y*v.y + v.z*v.z + v.w*v.w;
    }
    __shared__ float r1[256], r2[256];
    r1[threadIdx.x] = s; r2[threadIdx.x] = ss;
    __syncthreads();
    for (int off = 128; off > 0; off >>= 1) {
        if (threadIdx.x < off) {
            r1[threadIdx.x] += r1[threadIdx.x + off];
            r2[threadIdx.x] += r2[threadIdx.x + off];
        }
        __syncthreads();
    }
    if (threadIdx.x == 0) {
        float mean = r1[0] * (1.f / 16384.f);
        float var  = r2[0] * (1.f / 16384.f) - mean * mean;
        stats[bg * 2 + 0] = mean;
        stats[bg * 2 + 1] = rsqrtf(var + EPS_);
    }
}

// ---------------------------------------------------------------------------
// fp32 -> bf16 elementwise convert (weights; once per launch).
// ---------------------------------------------------------------------------
__global__ __launch_bounds__(256) void cvt_bf16_kernel(
    const float* __restrict__ src, unsigned short* __restrict__ dst, int n4)
{
    int i = blockIdx.x * 256 + threadIdx.x;
    if (i >= n4) return;
    float4 v = ((const float4*)src)[i];
    uint2 o; o.x = pack2(v.x, v.y); o.y = pack2(v.z, v.w);
    ((uint2*)dst)[i] = o;
}

// ---------------------------------------------------------------------------
// hhatT producer: x[b][c][n] fp32 (coalesced reads) -> GN affine ->
// hhatT[bz][n][c] bf16 via 64x64 LDS tile transpose.
// ---------------------------------------------------------------------------
__global__ __launch_bounds__(256) void hhatT_kernel(
    const float* __restrict__ x, const float* __restrict__ stats,
    const float* __restrict__ nw, const float* __restrict__ nbias,
    unsigned short* __restrict__ hhatT, long sH, int b0)
{
    int bz = blockIdx.z, b = b0 + bz;
    int nt = blockIdx.x * 64, ct = blockIdx.y * 64;
    const float* xb = x + (size_t)b * C_ * N_;
    const float* st = stats + b * 2 * G_;

    __shared__ float T[64][65];
    int tid = threadIdx.x;

    #pragma unroll
    for (int p = 0; p < 4; ++p) {
        int c = p * 16 + (tid >> 4);
        int n4 = (tid & 15) * 4;
        float4 v = *(const float4*)&xb[(size_t)(ct + c) * N_ + nt + n4];
        int g = (ct + c) >> 4;
        float w0 = nw[ct + c] * st[g * 2 + 1];
        float bb = nbias[ct + c] - st[g * 2] * w0;
        T[c][n4]   = v.x * w0 + bb;
        T[c][n4+1] = v.y * w0 + bb;
        T[c][n4+2] = v.z * w0 + bb;
        T[c][n4+3] = v.w * w0 + bb;
    }
    __syncthreads();
    #pragma unroll
    for (int p = 0; p < 2; ++p) {
        int n  = p * 32 + (tid >> 3);
        int c8 = (tid & 7) * 8;
        short8 s;
        #pragma unroll
        for (int u = 0; u < 8; ++u) s[u] = (short)f2bf(T[c8 + u][n]);
        *(short8*)&hhatT[(size_t)bz * sH + (size_t)(nt + n) * C_ + ct + c8] = s;
    }
}

// ---------------------------------------------------------------------------
// 128x128 GEMM: D[row][col] = sum_k A[row][k] * B[col][k]  (+ epilogue)
// BK=32, 256 threads = 4 waves (2x2 of 64x64 sub-tiles). Manual staging:
// short8 global loads -> regs -> ds_write_b128; frags via ds_read_b128.
// EPI: 0 bf16 +bias[col] | 1 bf16 +bias[row] | 2 fp32 *scale | 3 bf16
//      4 fp32 +bias[row]+aux (residual)
// ---------------------------------------------------------------------------
template<int EPI>
__global__ __launch_bounds__(256) void gemm128(
    const unsigned short* __restrict__ A, long sA, int lda,
    const unsigned short* __restrict__ B, long sB, int ldb,
    void* __restrict__ Dv, long sD, int ldd,
    const float* __restrict__ bias,
    const float* __restrict__ aux, long sAux,
    int K, float scale)
{
    int bz = blockIdx.z;
    const unsigned short* Ab = A + (size_t)bz * sA + (size_t)blockIdx.x * 128 * lda;
    const unsigned short* Bb = B + (size_t)bz * sB + (size_t)blockIdx.y * 128 * ldb;

    __shared__ __align__(16) unsigned short As[128 * LRS];
    __shared__ __align__(16) unsigned short Bs[128 * LRS];

    int tid = threadIdx.x;
    int w = tid >> 6, lane = tid & 63;
    int lm = lane & 15, q = lane >> 4;
    int wrow = (w >> 1) * 64, wcol = (w & 1) * 64;

    f32x4 acc[4][4];
    #pragma unroll
    for (int i = 0; i < 4; ++i)
        #pragma unroll
        for (int j = 0; j < 4; ++j) acc[i][j] = (f32x4)(0.f);

    int srow = tid >> 2, skoff = (tid & 3) * 8;   // 64 rows x 32k per quarter

    for (int k0 = 0; k0 < K; k0 += 32) {
        short8 a0 = *(const short8*)(Ab + (size_t)srow        * lda + k0 + skoff);
        short8 a1 = *(const short8*)(Ab + (size_t)(64 + srow) * lda + k0 + skoff);
        short8 b0 = *(const short8*)(Bb + (size_t)srow        * ldb + k0 + skoff);
        short8 b1 = *(const short8*)(Bb + (size_t)(64 + srow) * ldb + k0 + skoff);
        __syncthreads();   // prev iter's frag reads complete
        *(short8*)&As[(size_t)srow        * LRS + skoff] = a0;
        *(short8*)&As[(size_t)(64 + srow) * LRS + skoff] = a1;
        *(short8*)&Bs[(size_t)srow        * LRS + skoff] = b0;
        *(short8*)&Bs[(size_t)(64 + srow) * LRS + skoff] = b1;
        __syncthreads();
        short8 af[4], bf[4];
        #pragma unroll
        for (int i = 0; i < 4; ++i)
            af[i] = *(const short8*)&As[(wrow + i * 16 + lm) * LRS + q * 8];
        #pragma unroll
        for (int j = 0; j < 4; ++j)
            bf[j] = *(const short8*)&Bs[(wcol + j * 16 + lm) * LRS + q * 8];
        #pragma unroll
        for (int i = 0; i < 4; ++i)
            #pragma unroll
            for (int j = 0; j < 4; ++j)
                acc[i][j] = __builtin_amdgcn_mfma_f32_16x16x32_bf16(
                    af[i], bf[j], acc[i][j], 0, 0, 0);
    }

    int grow = blockIdx.x * 128 + wrow;
    int gcol = blockIdx.y * 128 + wcol;

    #pragma unroll
    for (int j = 0; j < 4; ++j) {
        int col = gcol + j * 16 + lm;
        float cb = (EPI == 0) ? bias[col] : 0.f;
        #pragma unroll
        for (int i = 0; i < 4; ++i) {
            #pragma unroll
            for (int r = 0; r < 4; ++r) {
                int row = grow + i * 16 + q * 4 + r;
                float vle = acc[i][j][r];
                if constexpr (EPI == 0) {
                    vle += cb;
                    ((unsigned short*)Dv)[(size_t)bz * sD + (size_t)row * ldd + col] = f2bf(vle);
                } else if constexpr (EPI == 1) {
                    vle += bias[row];
                    ((unsigned short*)Dv)[(size_t)bz * sD + (size_t)row * ldd + col] = f2bf(vle);
                } else if constexpr (EPI == 2) {
                    ((float*)Dv)[(size_t)bz * sD + (size_t)row * ldd + col] = vle * scale;
                } else if constexpr (EPI == 3) {
                    ((unsigned short*)Dv)[(size_t)bz * sD + (size_t)row * ldd + col] = f2bf(vle);
                } else {
                    vle += bias[row] + aux[(size_t)bz * sAux + (size_t)row * ldd + col];
                    ((float*)Dv)[(size_t)bz * sD + (size_t)row * ldd + col] = vle;
                }
            }
        }
    }
}

// ---------------------------------------------------------------------------
// Softmax: fp32 scores row in, bf16 attn row out. grid (N_, nb).
// ---------------------------------------------------------------------------
__global__ __launch_bounds__(256) void softmax_kernel(
    const float* __restrict__ scores, long sSc,
    unsigned short* __restrict__ attn, long sAt)
{
    int n = blockIdx.x, bz = blockIdx.y;
    const float4* p = (const float4*)(scores + (size_t)bz * sSc + (size_t)n * N_);
    int tid = threadIdx.x;
    float4 v = p[tid];

    __shared__ float red[256];
    float m = fmaxf(fmaxf(v.x, v.y), fmaxf(v.z, v.w));
    red[tid] = m; __syncthreads();
    for (int off = 128; off > 0; off >>= 1) {
        if (tid < off) red[tid] = fmaxf(red[tid], red[tid + off]);
        __syncthreads();
    }
    m = red[0]; __syncthreads();

    v.x = expf(v.x - m); v.y = expf(v.y - m);
    v.z = expf(v.z - m); v.w = expf(v.w - m);
    red[tid] = v.x + v.y + v.z + v.w; __syncthreads();
    for (int off = 128; off > 0; off >>= 1) {
        if (tid < off) red[tid] += red[tid + off];
        __syncthreads();
    }
    float inv = 1.f / red[0];
    uint2 o;
    o.x = pack2(v.x * inv, v.y * inv);
    o.y = pack2(v.z * inv, v.w * inv);
    ((uint2*)(attn + (size_t)bz * sAt + (size_t)n * N_))[tid] = o;
}

// ---------------------------------------------------------------------------
extern "C" void kernel_launch(void* const* d_in, const int* in_sizes, int n_in,
                              void* d_out, int out_size, void* d_ws, size_t ws_size,
                              hipStream_t stream) {
    const float* x      = (const float*)d_in[0];
    const float* norm_w = (const float*)d_in[1];
    const float* norm_b = (const float*)d_in[2];
    const float* qkv_w  = (const float*)d_in[3];
    const float* qkv_b  = (const float*)d_in[4];
    const float* proj_w = (const float*)d_in[5];
    const float* proj_b = (const float*)d_in[6];
    float* out = (float*)d_out;

    // Fixed region: stats (8 KB) + bf16 weights (2 MB).
    char* ws = (char*)d_ws;
    float* stats = (float*)ws;
    unsigned short* wqkv  = (unsigned short*)(ws + 8192);   // 1536x512
    unsigned short* wproj = wqkv + (size_t)OC3_ * C_;       // 512x512
    char* base = (char*)(wproj + (size_t)C_ * C_);
    const size_t fixed = 8192 + (size_t)OC3_ * C_ * 2 + (size_t)C_ * C_ * 2; // 2,105,344

    // Per-batch aliased region: 8 MB.
    //   [0,2M)  qkT bf16 [n][1024]   -> after softmax reused as attn bf16 [n][m]
    //   [2,3M)  v bf16 [c][n]
    //   [3,4M)  hhatT bf16 [n][c]    -> after GEMM2 reused as houtT bf16 [n][c]
    //   [4,8M)  scores fp32 [n][m]
    const size_t REG = 8u << 20;              // bytes per batch
    const long RSH = (long)(REG / 2);         // region stride in shorts (4194304)
    const long RSF = (long)(REG / 4);         // region stride in floats (2097152)

    size_t avail = ws_size > fixed ? ws_size - fixed : 0;
    int chunk = (int)(avail / REG);
    if (chunk < 1) chunk = 1;   // chunk=1 footprint 10.2 MB < proven-good 12.59 MB
    if (chunk > B_) chunk = B_;

    gn_stats_kernel<<<dim3(B_ * G_), dim3(256), 0, stream>>>(x, stats);
    cvt_bf16_kernel<<<dim3((OC3_ * C_ / 4 + 255) / 256), dim3(256), 0, stream>>>(
        qkv_w, wqkv, OC3_ * C_ / 4);
    cvt_bf16_kernel<<<dim3((C_ * C_ / 4 + 255) / 256), dim3(256), 0, stream>>>(
        proj_w, wproj, C_ * C_ / 4);

    const float scale = 0.044194173824159216f;  // 512^-0.5

    unsigned short* qkT   = (unsigned short*)base;
    unsigned short* attn  = (unsigned short*)base;               // aliases qkT
    unsigned short* vbuf  = (unsigned short*)(base + (2u << 20));
    unsigned short* hhatT = (unsigned short*)(base + (3u << 20));
    unsigned short* houtT = (unsigned short*)(base + (3u << 20)); // aliases hhatT
    float*          sc    = (float*)(base + (4u << 20));

    for (int b0 = 0; b0 < B_; b0 += chunk) {
        int nb = B_ - b0 < chunk ? B_ - b0 : chunk;

        hhatT_kernel<<<dim3(N_/64, C_/64, nb), dim3(256), 0, stream>>>(
            x, stats, norm_w, norm_b, hhatT, RSH, b0);

        // GEMM1a: qkT[n][o] = hhatT[n][:] . Wqk[o][:]   (o in [0,1024))
        gemm128<0><<<dim3(8, 8, nb), dim3(256), 0, stream>>>(
            hhatT, RSH, C_,  wqkv, 0, C_,
            qkT, RSH, 1024,  qkv_b, nullptr, 0, C_, 0.f);

        // GEMM1b: v[c][n] = Wv[c][:] . hhatT[n][:]
        gemm128<1><<<dim3(4, 8, nb), dim3(256), 0, stream>>>(
            wqkv + (size_t)1024 * C_, 0, C_,  hhatT, RSH, C_,
            vbuf, RSH, N_,  qkv_b + 1024, nullptr, 0, C_, 0.f);

        // GEMM2: scores[n][m] = scale * qkT[n][0:512] . qkT[m][512:1024]
        gemm128<2><<<dim3(8, 8, nb), dim3(256), 0, stream>>>(
            qkT, RSH, 1024,  qkT + 512, RSH, 1024,
            sc, RSF, N_,  nullptr, nullptr, 0, C_, scale);

        softmax_kernel<<<dim3(N_, nb), dim3(256), 0, stream>>>(sc, RSF, attn, RSH);

        // GEMM3: houtT[n][c] = attn[n][:] . v[c][:]   (K = 1024)
        gemm128<3><<<dim3(8, 4, nb), dim3(256), 0, stream>>>(
            attn, RSH, N_,  vbuf, RSH, N_,
            houtT, RSH, C_,  nullptr, nullptr, 0, N_, 0.f);

        // GEMM4: out[o][n] = pw[o][:] . houtT[n][:] + pb[o] + x[o][n]
        gemm128<4><<<dim3(4, 8, nb), dim3(256), 0, stream>>>(
            wproj, 0, C_,  houtT, RSH, C_,
            out + (size_t)b0 * C_ * N_, (long)C_ * N_, N_,
            proj_b, x + (size_t)b0 * C_ * N_, (long)C_ * N_, C_, 0.f);
    }
}

// Round 6
// 566.148 us; speedup vs baseline: 5.0091x; 1.0131x over previous
//
#include <hip/hip_runtime.h>
#include <math.h>

// Problem constants
#define B_ 32
#define C_ 512
#define G_ 32
#define N_ 1024          // H*W
#define OC3_ 1536        // 3*C
#define EPS_ 1e-5f

typedef __attribute__((ext_vector_type(8))) short short8;
typedef __attribute__((ext_vector_type(4))) float f32x4;

// fp32 -> bf16 RNE
__device__ inline unsigned short f2bf(float f) {
    unsigned u = __builtin_bit_cast(unsigned, f);
    u += 0x7fffu + ((u >> 16) & 1u);
    return (unsigned short)(u >> 16);
}
__device__ inline unsigned pack2(float lo, float hi) {
    return (unsigned)f2bf(lo) | ((unsigned)f2bf(hi) << 16);
}

// async global->LDS 16 B per lane (gfx950). Contract (m104/m108): LDS dest is
// wave-uniform base + lane*16; every call site uses &lds[tid*8] (shorts) so a
// wave's 64 lanes cover 1024 contiguous bytes. LDS row stride MUST be
// unpadded 32 shorts for this layout.
typedef const __attribute__((address_space(1))) unsigned int* gas_u32;
typedef __attribute__((address_space(3))) unsigned int* las_u32;
__device__ __forceinline__ void cp16(unsigned short* lds, const unsigned short* g) {
    __builtin_amdgcn_global_load_lds((gas_u32)g, (las_u32)lds, 16, 0, 0);
}

// ---------------------------------------------------------------------------
// GroupNorm statistics. One block per (b,g): 16 ch x 1024 = 16384 floats.
// ---------------------------------------------------------------------------
__global__ __launch_bounds__(256) void gn_stats_kernel(
    const float* __restrict__ x, float* __restrict__ stats)
{
    int bg = blockIdx.x;
    const float4* xv = (const float4*)(x + (size_t)bg * 16 * N_);
    float s = 0.f, ss = 0.f;
    for (int i = threadIdx.x; i < 4096; i += 256) {
        float4 v = xv[i];
        s  += v.x + v.y + v.z + v.w;
        ss += v.x*v.x + v.y*v.y + v.z*v.z + v.w*v.w;
    }
    __shared__ float r1[256], r2[256];
    r1[threadIdx.x] = s; r2[threadIdx.x] = ss;
    __syncthreads();
    for (int off = 128; off > 0; off >>= 1) {
        if (threadIdx.x < off) {
            r1[threadIdx.x] += r1[threadIdx.x + off];
            r2[threadIdx.x] += r2[threadIdx.x + off];
        }
        __syncthreads();
    }
    if (threadIdx.x == 0) {
        float mean = r1[0] * (1.f / 16384.f);
        float var  = r2[0] * (1.f / 16384.f) - mean * mean;
        stats[bg * 2 + 0] = mean;
        stats[bg * 2 + 1] = rsqrtf(var + EPS_);
    }
}

// ---------------------------------------------------------------------------
// fp32 -> bf16 elementwise convert (weights; once per launch).
// ---------------------------------------------------------------------------
__global__ __launch_bounds__(256) void cvt_bf16_kernel(
    const float* __restrict__ src, unsigned short* __restrict__ dst, int n4)
{
    int i = blockIdx.x * 256 + threadIdx.x;
    if (i >= n4) return;
    float4 v = ((const float4*)src)[i];
    uint2 o; o.x = pack2(v.x, v.y); o.y = pack2(v.z, v.w);
    ((uint2*)dst)[i] = o;
}

// ---------------------------------------------------------------------------
// hhatT producer: x[b][c][n] fp32 (coalesced reads) -> GN affine ->
// hhatT[bz][n][c] bf16 via 64x64 LDS tile transpose.
// ---------------------------------------------------------------------------
__global__ __launch_bounds__(256) void hhatT_kernel(
    const float* __restrict__ x, const float* __restrict__ stats,
    const float* __restrict__ nw, const float* __restrict__ nbias,
    unsigned short* __restrict__ hhatT, long sH, int b0)
{
    int bz = blockIdx.z, b = b0 + bz;
    int nt = blockIdx.x * 64, ct = blockIdx.y * 64;
    const float* xb = x + (size_t)b * C_ * N_;
    const float* st = stats + b * 2 * G_;

    __shared__ float T[64][65];
    int tid = threadIdx.x;

    #pragma unroll
    for (int p = 0; p < 4; ++p) {
        int c = p * 16 + (tid >> 4);
        int n4 = (tid & 15) * 4;
        float4 v = *(const float4*)&xb[(size_t)(ct + c) * N_ + nt + n4];
        int g = (ct + c) >> 4;
        float w0 = nw[ct + c] * st[g * 2 + 1];
        float bb = nbias[ct + c] - st[g * 2] * w0;
        T[c][n4]   = v.x * w0 + bb;
        T[c][n4+1] = v.y * w0 + bb;
        T[c][n4+2] = v.z * w0 + bb;
        T[c][n4+3] = v.w * w0 + bb;
    }
    __syncthreads();
    #pragma unroll
    for (int p = 0; p < 2; ++p) {
        int n  = p * 32 + (tid >> 3);
        int c8 = (tid & 7) * 8;
        short8 s;
        #pragma unroll
        for (int u = 0; u < 8; ++u) s[u] = (short)f2bf(T[c8 + u][n]);
        *(short8*)&hhatT[(size_t)bz * sH + (size_t)(nt + n) * C_ + ct + c8] = s;
    }
}

// ---------------------------------------------------------------------------
// 128x128 GEMM: D[row][col] = sum_k A[row][k] * B[col][k]  (+ epilogue)
// BK=32, 256 threads = 4 waves (2x2 of 64x64 sub-tiles). m97 staging:
// global_load_lds width-16 into unpadded stride-32 LDS; ds_read_b128 frags.
// EPI: 0 bf16 +bias[col] | 1 bf16 +bias[row] | 2 fp32 *scale | 3 bf16
//      4 fp32 +bias[row]+aux (residual)
// ---------------------------------------------------------------------------
template<int EPI>
__global__ __launch_bounds__(256) void gemm128(
    const unsigned short* __restrict__ A, long sA, int lda,
    const unsigned short* __restrict__ B, long sB, int ldb,
    void* __restrict__ Dv, long sD, int ldd,
    const float* __restrict__ bias,
    const float* __restrict__ aux, long sAux,
    int K, float scale)
{
    int bz = blockIdx.z;
    const unsigned short* Ab = A + (size_t)bz * sA + (size_t)blockIdx.x * 128 * lda;
    const unsigned short* Bb = B + (size_t)bz * sB + (size_t)blockIdx.y * 128 * ldb;

    __shared__ __align__(16) unsigned short As[128 * 32];
    __shared__ __align__(16) unsigned short Bs[128 * 32];

    int tid = threadIdx.x;
    int w = tid >> 6, lane = tid & 63;
    int lm = lane & 15, q = lane >> 4;
    int wrow = (w >> 1) * 64, wcol = (w & 1) * 64;

    f32x4 acc[4][4];
    #pragma unroll
    for (int i = 0; i < 4; ++i)
        #pragma unroll
        for (int j = 0; j < 4; ++j) acc[i][j] = (f32x4)(0.f);

    int srow = tid >> 2, skoff = (tid & 3) * 8;   // 64 rows x 32k per quarter

    for (int k0 = 0; k0 < K; k0 += 32) {
        cp16(&As[tid * 8],        Ab + (size_t)srow        * lda + k0 + skoff);
        cp16(&As[2048 + tid * 8], Ab + (size_t)(64 + srow) * lda + k0 + skoff);
        cp16(&Bs[tid * 8],        Bb + (size_t)srow        * ldb + k0 + skoff);
        cp16(&Bs[2048 + tid * 8], Bb + (size_t)(64 + srow) * ldb + k0 + skoff);
        __syncthreads();   // drains vmcnt (DMA done) + lgkmcnt
        short8 af[4], bf[4];
        #pragma unroll
        for (int i = 0; i < 4; ++i)
            af[i] = *(const short8*)&As[(wrow + i * 16 + lm) * 32 + q * 8];
        #pragma unroll
        for (int j = 0; j < 4; ++j)
            bf[j] = *(const short8*)&Bs[(wcol + j * 16 + lm) * 32 + q * 8];
        #pragma unroll
        for (int i = 0; i < 4; ++i)
            #pragma unroll
            for (int j = 0; j < 4; ++j)
                acc[i][j] = __builtin_amdgcn_mfma_f32_16x16x32_bf16(
                    af[i], bf[j], acc[i][j], 0, 0, 0);
        __syncthreads();   // frag reads done before next iter's DMA overwrites
    }

    int grow = blockIdx.x * 128 + wrow;
    int gcol = blockIdx.y * 128 + wcol;

    #pragma unroll
    for (int j = 0; j < 4; ++j) {
        int col = gcol + j * 16 + lm;
        float cb = (EPI == 0) ? bias[col] : 0.f;
        #pragma unroll
        for (int i = 0; i < 4; ++i) {
            #pragma unroll
            for (int r = 0; r < 4; ++r) {
                int row = grow + i * 16 + q * 4 + r;
                float vle = acc[i][j][r];
                if constexpr (EPI == 0) {
                    vle += cb;
                    ((unsigned short*)Dv)[(size_t)bz * sD + (size_t)row * ldd + col] = f2bf(vle);
                } else if constexpr (EPI == 1) {
                    vle += bias[row];
                    ((unsigned short*)Dv)[(size_t)bz * sD + (size_t)row * ldd + col] = f2bf(vle);
                } else if constexpr (EPI == 2) {
                    ((float*)Dv)[(size_t)bz * sD + (size_t)row * ldd + col] = vle * scale;
                } else if constexpr (EPI == 3) {
                    ((unsigned short*)Dv)[(size_t)bz * sD + (size_t)row * ldd + col] = f2bf(vle);
                } else {
                    vle += bias[row] + aux[(size_t)bz * sAux + (size_t)row * ldd + col];
                    ((float*)Dv)[(size_t)bz * sD + (size_t)row * ldd + col] = vle;
                }
            }
        }
    }
}

// ---------------------------------------------------------------------------
// Softmax: fp32 scores row in, bf16 attn row out. grid (N_, nb).
// ---------------------------------------------------------------------------
__global__ __launch_bounds__(256) void softmax_kernel(
    const float* __restrict__ scores, long sSc,
    unsigned short* __restrict__ attn, long sAt)
{
    int n = blockIdx.x, bz = blockIdx.y;
    const float4* p = (const float4*)(scores + (size_t)bz * sSc + (size_t)n * N_);
    int tid = threadIdx.x;
    float4 v = p[tid];

    __shared__ float red[256];
    float m = fmaxf(fmaxf(v.x, v.y), fmaxf(v.z, v.w));
    red[tid] = m; __syncthreads();
    for (int off = 128; off > 0; off >>= 1) {
        if (tid < off) red[tid] = fmaxf(red[tid], red[tid + off]);
        __syncthreads();
    }
    m = red[0]; __syncthreads();

    v.x = expf(v.x - m); v.y = expf(v.y - m);
    v.z = expf(v.z - m); v.w = expf(v.w - m);
    red[tid] = v.x + v.y + v.z + v.w; __syncthreads();
    for (int off = 128; off > 0; off >>= 1) {
        if (tid < off) red[tid] += red[tid + off];
        __syncthreads();
    }
    float inv = 1.f / red[0];
    uint2 o;
    o.x = pack2(v.x * inv, v.y * inv);
    o.y = pack2(v.z * inv, v.w * inv);
    ((uint2*)(attn + (size_t)bz * sAt + (size_t)n * N_))[tid] = o;
}

// ---------------------------------------------------------------------------
extern "C" void kernel_launch(void* const* d_in, const int* in_sizes, int n_in,
                              void* d_out, int out_size, void* d_ws, size_t ws_size,
                              hipStream_t stream) {
    const float* x      = (const float*)d_in[0];
    const float* norm_w = (const float*)d_in[1];
    const float* norm_b = (const float*)d_in[2];
    const float* qkv_w  = (const float*)d_in[3];
    const float* qkv_b  = (const float*)d_in[4];
    const float* proj_w = (const float*)d_in[5];
    const float* proj_b = (const float*)d_in[6];
    float* out = (float*)d_out;

    // Fixed region: stats (8 KB) + bf16 weights (2 MB).
    char* ws = (char*)d_ws;
    float* stats = (float*)ws;
    unsigned short* wqkv  = (unsigned short*)(ws + 8192);   // 1536x512
    unsigned short* wproj = wqkv + (size_t)OC3_ * C_;       // 512x512
    char* base = (char*)(wproj + (size_t)C_ * C_);
    const size_t fixed = 8192 + (size_t)OC3_ * C_ * 2 + (size_t)C_ * C_ * 2; // 2,105,344

    // Per-batch aliased region: 8 MB (identical to Round 5, proven).
    //   [0,2M)  qkT bf16 [n][1024]   -> after softmax reused as attn bf16 [n][m]
    //   [2,3M)  v bf16 [c][n]
    //   [3,4M)  hhatT bf16 [n][c]    -> after GEMM2 reused as houtT bf16 [n][c]
    //   [4,8M)  scores fp32 [n][m]
    const size_t REG = 8u << 20;
    const long RSH = (long)(REG / 2);         // region stride in shorts
    const long RSF = (long)(REG / 4);         // region stride in floats

    size_t avail = ws_size > fixed ? ws_size - fixed : 0;
    int chunk = (int)(avail / REG);
    if (chunk < 1) chunk = 1;
    if (chunk > B_) chunk = B_;

    gn_stats_kernel<<<dim3(B_ * G_), dim3(256), 0, stream>>>(x, stats);
    cvt_bf16_kernel<<<dim3((OC3_ * C_ / 4 + 255) / 256), dim3(256), 0, stream>>>(
        qkv_w, wqkv, OC3_ * C_ / 4);
    cvt_bf16_kernel<<<dim3((C_ * C_ / 4 + 255) / 256), dim3(256), 0, stream>>>(
        proj_w, wproj, C_ * C_ / 4);

    const float scale = 0.044194173824159216f;  // 512^-0.5

    unsigned short* qkT   = (unsigned short*)base;
    unsigned short* attn  = (unsigned short*)base;               // aliases qkT
    unsigned short* vbuf  = (unsigned short*)(base + (2u << 20));
    unsigned short* hhatT = (unsigned short*)(base + (3u << 20));
    unsigned short* houtT = (unsigned short*)(base + (3u << 20)); // aliases hhatT
    float*          sc    = (float*)(base + (4u << 20));

    for (int b0 = 0; b0 < B_; b0 += chunk) {
        int nb = B_ - b0 < chunk ? B_ - b0 : chunk;

        hhatT_kernel<<<dim3(N_/64, C_/64, nb), dim3(256), 0, stream>>>(
            x, stats, norm_w, norm_b, hhatT, RSH, b0);

        // GEMM1a: qkT[n][o] = hhatT[n][:] . Wqk[o][:]   (o in [0,1024))
        gemm128<0><<<dim3(8, 8, nb), dim3(256), 0, stream>>>(
            hhatT, RSH, C_,  wqkv, 0, C_,
            qkT, RSH, 1024,  qkv_b, nullptr, 0, C_, 0.f);

        // GEMM1b: v[c][n] = Wv[c][:] . hhatT[n][:]
        gemm128<1><<<dim3(4, 8, nb), dim3(256), 0, stream>>>(
            wqkv + (size_t)1024 * C_, 0, C_,  hhatT, RSH, C_,
            vbuf, RSH, N_,  qkv_b + 1024, nullptr, 0, C_, 0.f);

        // GEMM2: scores[n][m] = scale * qkT[n][0:512] . qkT[m][512:1024]
        gemm128<2><<<dim3(8, 8, nb), dim3(256), 0, stream>>>(
            qkT, RSH, 1024,  qkT + 512, RSH, 1024,
            sc, RSF, N_,  nullptr, nullptr, 0, C_, scale);

        softmax_kernel<<<dim3(N_, nb), dim3(256), 0, stream>>>(sc, RSF, attn, RSH);

        // GEMM3: houtT[n][c] = attn[n][:] . v[c][:]   (K = 1024)
        gemm128<3><<<dim3(8, 4, nb), dim3(256), 0, stream>>>(
            attn, RSH, N_,  vbuf, RSH, N_,
            houtT, RSH, C_,  nullptr, nullptr, 0, N_, 0.f);

        // GEMM4: out[o][n] = pw[o][:] . houtT[n][:] + pb[o] + x[o][n]
        gemm128<4><<<dim3(4, 8, nb), dim3(256), 0, stream>>>(
            wproj, 0, C_,  houtT, RSH, C_,
            out + (size_t)b0 * C_ * N_, (long)C_ * N_, N_,
            proj_b, x + (size_t)b0 * C_ * N_, (long)C_ * N_, C_, 0.f);
    }
}

// Round 7
// 434.798 us; speedup vs baseline: 6.5223x; 1.3021x over previous
//
#include <hip/hip_runtime.h>
#include <math.h>

// Problem constants
#define B_ 32
#define C_ 512
#define G_ 32
#define N_ 1024          // H*W
#define OC3_ 1536        // 3*C
#define EPS_ 1e-5f

typedef __attribute__((ext_vector_type(8))) short short8;
typedef __attribute__((ext_vector_type(4))) float f32x4;

// fp32 -> bf16 RNE
__device__ inline unsigned short f2bf(float f) {
    unsigned u = __builtin_bit_cast(unsigned, f);
    u += 0x7fffu + ((u >> 16) & 1u);
    return (unsigned short)(u >> 16);
}
__device__ inline unsigned pack2(float lo, float hi) {
    return (unsigned)f2bf(lo) | ((unsigned)f2bf(hi) << 16);
}
__device__ inline float bf2f(unsigned short u) {
    return __builtin_bit_cast(float, ((unsigned)u) << 16);
}

// async global->LDS 16 B per lane (gfx950). LDS dest = wave-uniform base +
// lane*16; all call sites use &lds[tid*8] (shorts). Row stride must stay an
// unpadded 32 shorts; bank conflicts on frag reads are handled by the XOR
// chunk swizzle below instead of padding.
typedef const __attribute__((address_space(1))) unsigned int* gas_u32;
typedef __attribute__((address_space(3))) unsigned int* las_u32;
__device__ __forceinline__ void cp16(unsigned short* lds, const unsigned short* g) {
    __builtin_amdgcn_global_load_lds((gas_u32)g, (las_u32)lds, 16, 0, 0);
}

// ---------------------------------------------------------------------------
// GroupNorm statistics. One block per (b,g): 16 ch x 1024 = 16384 floats.
// ---------------------------------------------------------------------------
__global__ __launch_bounds__(256) void gn_stats_kernel(
    const float* __restrict__ x, float* __restrict__ stats)
{
    int bg = blockIdx.x;
    const float4* xv = (const float4*)(x + (size_t)bg * 16 * N_);
    float s = 0.f, ss = 0.f;
    for (int i = threadIdx.x; i < 4096; i += 256) {
        float4 v = xv[i];
        s  += v.x + v.y + v.z + v.w;
        ss += v.x*v.x + v.y*v.y + v.z*v.z + v.w*v.w;
    }
    __shared__ float r1[256], r2[256];
    r1[threadIdx.x] = s; r2[threadIdx.x] = ss;
    __syncthreads();
    for (int off = 128; off > 0; off >>= 1) {
        if (threadIdx.x < off) {
            r1[threadIdx.x] += r1[threadIdx.x + off];
            r2[threadIdx.x] += r2[threadIdx.x + off];
        }
        __syncthreads();
    }
    if (threadIdx.x == 0) {
        float mean = r1[0] * (1.f / 16384.f);
        float var  = r2[0] * (1.f / 16384.f) - mean * mean;
        stats[bg * 2 + 0] = mean;
        stats[bg * 2 + 1] = rsqrtf(var + EPS_);
    }
}

// ---------------------------------------------------------------------------
// fp32 -> bf16 elementwise convert (weights; once per launch).
// ---------------------------------------------------------------------------
__global__ __launch_bounds__(256) void cvt_bf16_kernel(
    const float* __restrict__ src, unsigned short* __restrict__ dst, int n4)
{
    int i = blockIdx.x * 256 + threadIdx.x;
    if (i >= n4) return;
    float4 v = ((const float4*)src)[i];
    uint2 o; o.x = pack2(v.x, v.y); o.y = pack2(v.z, v.w);
    ((uint2*)dst)[i] = o;
}

// ---------------------------------------------------------------------------
// hhatT producer: x[b][c][n] fp32 (coalesced reads) -> GN affine ->
// hhatT[bz][n][c] bf16 via 64x64 LDS tile transpose.
// ---------------------------------------------------------------------------
__global__ __launch_bounds__(256) void hhatT_kernel(
    const float* __restrict__ x, const float* __restrict__ stats,
    const float* __restrict__ nw, const float* __restrict__ nbias,
    unsigned short* __restrict__ hhatT, long sH, int b0)
{
    int bz = blockIdx.z, b = b0 + bz;
    int nt = blockIdx.x * 64, ct = blockIdx.y * 64;
    const float* xb = x + (size_t)b * C_ * N_;
    const float* st = stats + b * 2 * G_;

    __shared__ float T[64][65];
    int tid = threadIdx.x;

    #pragma unroll
    for (int p = 0; p < 4; ++p) {
        int c = p * 16 + (tid >> 4);
        int n4 = (tid & 15) * 4;
        float4 v = *(const float4*)&xb[(size_t)(ct + c) * N_ + nt + n4];
        int g = (ct + c) >> 4;
        float w0 = nw[ct + c] * st[g * 2 + 1];
        float bb = nbias[ct + c] - st[g * 2] * w0;
        T[c][n4]   = v.x * w0 + bb;
        T[c][n4+1] = v.y * w0 + bb;
        T[c][n4+2] = v.z * w0 + bb;
        T[c][n4+3] = v.w * w0 + bb;
    }
    __syncthreads();
    #pragma unroll
    for (int p = 0; p < 2; ++p) {
        int n  = p * 32 + (tid >> 3);
        int c8 = (tid & 7) * 8;
        short8 s;
        #pragma unroll
        for (int u = 0; u < 8; ++u) s[u] = (short)f2bf(T[c8 + u][n]);
        *(short8*)&hhatT[(size_t)bz * sH + (size_t)(nt + n) * C_ + ct + c8] = s;
    }
}

// ---------------------------------------------------------------------------
// 128x128 GEMM: D[row][col] = sum_k A[row][k] * B[col][k]  (+ epilogue)
// BK=32, 4 waves (2x2 of 64x64). global_load_lds width-16 staging with XOR
// chunk swizzle: global chunk kc of row R is stored at physical chunk
// kc ^ ((R>>1)&3), so frag ds_read_b128 hits each bank exactly 2x (free).
// EPI: 0 bf16 +bias[col] | 1 bf16 +bias[row] | 2 bf16 *scale | 3 bf16
//      4 fp32 +bias[row]+aux (residual)
// ---------------------------------------------------------------------------
template<int EPI>
__global__ __launch_bounds__(256) void gemm128(
    const unsigned short* __restrict__ A, long sA, int lda,
    const unsigned short* __restrict__ B, long sB, int ldb,
    void* __restrict__ Dv, long sD, int ldd,
    const float* __restrict__ bias,
    const float* __restrict__ aux, long sAux,
    int K, float scale)
{
    int bz = blockIdx.z;
    const unsigned short* Ab = A + (size_t)bz * sA + (size_t)blockIdx.x * 128 * lda;
    const unsigned short* Bb = B + (size_t)bz * sB + (size_t)blockIdx.y * 128 * ldb;

    __shared__ __align__(16) unsigned short As[128 * 32];
    __shared__ __align__(16) unsigned short Bs[128 * 32];

    int tid = threadIdx.x;
    int w = tid >> 6, lane = tid & 63;
    int lm = lane & 15, q = lane >> 4;
    int wrow = (w >> 1) * 64, wcol = (w & 1) * 64;

    f32x4 acc[4][4];
    #pragma unroll
    for (int i = 0; i < 4; ++i)
        #pragma unroll
        for (int j = 0; j < 4; ++j) acc[i][j] = (f32x4)(0.f);

    int srow = tid >> 2;                              // staging row (0..63)
    int skc  = (((tid & 3) ^ ((tid >> 3) & 3))) * 8;  // swizzled global chunk
    int fco  = (q ^ ((lm >> 1) & 3)) * 8;             // frag physical chunk

    for (int k0 = 0; k0 < K; k0 += 32) {
        cp16(&As[tid * 8],        Ab + (size_t)srow        * lda + k0 + skc);
        cp16(&As[2048 + tid * 8], Ab + (size_t)(64 + srow) * lda + k0 + skc);
        cp16(&Bs[tid * 8],        Bb + (size_t)srow        * ldb + k0 + skc);
        cp16(&Bs[2048 + tid * 8], Bb + (size_t)(64 + srow) * ldb + k0 + skc);
        __syncthreads();   // drains vmcnt (DMA done)
        short8 af[4], bf[4];
        #pragma unroll
        for (int i = 0; i < 4; ++i)
            af[i] = *(const short8*)&As[(wrow + i * 16 + lm) * 32 + fco];
        #pragma unroll
        for (int j = 0; j < 4; ++j)
            bf[j] = *(const short8*)&Bs[(wcol + j * 16 + lm) * 32 + fco];
        #pragma unroll
        for (int i = 0; i < 4; ++i)
            #pragma unroll
            for (int j = 0; j < 4; ++j)
                acc[i][j] = __builtin_amdgcn_mfma_f32_16x16x32_bf16(
                    af[i], bf[j], acc[i][j], 0, 0, 0);
        __syncthreads();   // frag reads done before next iter's DMA overwrites
    }

    int grow = blockIdx.x * 128 + wrow;
    int gcol = blockIdx.y * 128 + wcol;

    #pragma unroll
    for (int j = 0; j < 4; ++j) {
        int col = gcol + j * 16 + lm;
        float cb = (EPI == 0) ? bias[col] : 0.f;
        #pragma unroll
        for (int i = 0; i < 4; ++i) {
            #pragma unroll
            for (int r = 0; r < 4; ++r) {
                int row = grow + i * 16 + q * 4 + r;
                float vle = acc[i][j][r];
                if constexpr (EPI == 0) {
                    vle += cb;
                    ((unsigned short*)Dv)[(size_t)bz * sD + (size_t)row * ldd + col] = f2bf(vle);
                } else if constexpr (EPI == 1) {
                    vle += bias[row];
                    ((unsigned short*)Dv)[(size_t)bz * sD + (size_t)row * ldd + col] = f2bf(vle);
                } else if constexpr (EPI == 2) {
                    ((unsigned short*)Dv)[(size_t)bz * sD + (size_t)row * ldd + col] = f2bf(vle * scale);
                } else if constexpr (EPI == 3) {
                    ((unsigned short*)Dv)[(size_t)bz * sD + (size_t)row * ldd + col] = f2bf(vle);
                } else {
                    vle += bias[row] + aux[(size_t)bz * sAux + (size_t)row * ldd + col];
                    ((float*)Dv)[(size_t)bz * sD + (size_t)row * ldd + col] = vle;
                }
            }
        }
    }
}

// ---------------------------------------------------------------------------
// Softmax: in-place on bf16 scores. One WAVE per row (16 elems/lane),
// shuffle reductions, no barriers. Block = 4 waves = 4 rows.
// ---------------------------------------------------------------------------
__global__ __launch_bounds__(256) void softmax_kernel(
    unsigned short* __restrict__ sc, long sSc)
{
    int bz = blockIdx.y;
    int row = blockIdx.x * 4 + (threadIdx.x >> 6);
    int lane = threadIdx.x & 63;
    unsigned short* p = sc + (size_t)bz * sSc + (size_t)row * N_ + lane * 16;

    short8 s0 = *(const short8*)p;
    short8 s1 = *(const short8*)(p + 8);
    float v[16];
    #pragma unroll
    for (int i = 0; i < 8; ++i) {
        v[i]     = bf2f((unsigned short)s0[i]);
        v[8 + i] = bf2f((unsigned short)s1[i]);
    }
    float m = v[0];
    #pragma unroll
    for (int i = 1; i < 16; ++i) m = fmaxf(m, v[i]);
    #pragma unroll
    for (int off = 32; off > 0; off >>= 1) m = fmaxf(m, __shfl_xor(m, off, 64));

    float sum = 0.f;
    #pragma unroll
    for (int i = 0; i < 16; ++i) { v[i] = __expf(v[i] - m); sum += v[i]; }
    #pragma unroll
    for (int off = 32; off > 0; off >>= 1) sum += __shfl_xor(sum, off, 64);
    float inv = 1.f / sum;

    short8 o0, o1;
    #pragma unroll
    for (int i = 0; i < 8; ++i) {
        o0[i] = (short)f2bf(v[i] * inv);
        o1[i] = (short)f2bf(v[8 + i] * inv);
    }
    *(short8*)p = o0;
    *(short8*)(p + 8) = o1;
}

// ---------------------------------------------------------------------------
extern "C" void kernel_launch(void* const* d_in, const int* in_sizes, int n_in,
                              void* d_out, int out_size, void* d_ws, size_t ws_size,
                              hipStream_t stream) {
    const float* x      = (const float*)d_in[0];
    const float* norm_w = (const float*)d_in[1];
    const float* norm_b = (const float*)d_in[2];
    const float* qkv_w  = (const float*)d_in[3];
    const float* qkv_b  = (const float*)d_in[4];
    const float* proj_w = (const float*)d_in[5];
    const float* proj_b = (const float*)d_in[6];
    float* out = (float*)d_out;

    // Fixed region: stats (8 KB) + bf16 weights (2 MB).
    char* ws = (char*)d_ws;
    float* stats = (float*)ws;
    unsigned short* wqkv  = (unsigned short*)(ws + 8192);   // 1536x512
    unsigned short* wproj = wqkv + (size_t)OC3_ * C_;       // 512x512
    char* base = (char*)(wproj + (size_t)C_ * C_);
    const size_t fixed = 8192 + (size_t)OC3_ * C_ * 2 + (size_t)C_ * C_ * 2;

    // Per-batch aliased region: 6 MB.
    //   [0,2M)  qkT bf16 [n][1024]
    //   [2,3M)  v bf16 [c][n]
    //   [3,4M)  hhatT bf16 [n][c]  -> after GEMM2 reused as houtT bf16 [n][c]
    //   [4,6M)  sc bf16 [n][m]     -> softmax in-place -> attn
    const size_t REG = 6u << 20;
    const long RSH = (long)(REG / 2);         // region stride in shorts

    size_t avail = ws_size > fixed ? ws_size - fixed : 0;
    int chunk = (int)(avail / REG);
    if (chunk < 1) chunk = 1;
    if (chunk > B_) chunk = B_;

    gn_stats_kernel<<<dim3(B_ * G_), dim3(256), 0, stream>>>(x, stats);
    cvt_bf16_kernel<<<dim3((OC3_ * C_ / 4 + 255) / 256), dim3(256), 0, stream>>>(
        qkv_w, wqkv, OC3_ * C_ / 4);
    cvt_bf16_kernel<<<dim3((C_ * C_ / 4 + 255) / 256), dim3(256), 0, stream>>>(
        proj_w, wproj, C_ * C_ / 4);

    const float scale = 0.044194173824159216f;  // 512^-0.5

    unsigned short* qkT   = (unsigned short*)base;
    unsigned short* vbuf  = (unsigned short*)(base + (2u << 20));
    unsigned short* hhatT = (unsigned short*)(base + (3u << 20));
    unsigned short* houtT = (unsigned short*)(base + (3u << 20)); // aliases hhatT
    unsigned short* sc    = (unsigned short*)(base + (4u << 20)); // scores/attn

    for (int b0 = 0; b0 < B_; b0 += chunk) {
        int nb = B_ - b0 < chunk ? B_ - b0 : chunk;

        hhatT_kernel<<<dim3(N_/64, C_/64, nb), dim3(256), 0, stream>>>(
            x, stats, norm_w, norm_b, hhatT, RSH, b0);

        // GEMM1a: qkT[n][o] = hhatT[n][:] . Wqk[o][:]   (o in [0,1024))
        gemm128<0><<<dim3(8, 8, nb), dim3(256), 0, stream>>>(
            hhatT, RSH, C_,  wqkv, 0, C_,
            qkT, RSH, 1024,  qkv_b, nullptr, 0, C_, 0.f);

        // GEMM1b: v[c][n] = Wv[c][:] . hhatT[n][:]
        gemm128<1><<<dim3(4, 8, nb), dim3(256), 0, stream>>>(
            wqkv + (size_t)1024 * C_, 0, C_,  hhatT, RSH, C_,
            vbuf, RSH, N_,  qkv_b + 1024, nullptr, 0, C_, 0.f);

        // GEMM2: sc[n][m] = bf16( scale * qkT[n][0:512] . qkT[m][512:1024] )
        gemm128<2><<<dim3(8, 8, nb), dim3(256), 0, stream>>>(
            qkT, RSH, 1024,  qkT + 512, RSH, 1024,
            sc, RSH, N_,  nullptr, nullptr, 0, C_, scale);

        softmax_kernel<<<dim3(N_/4, nb), dim3(256), 0, stream>>>(sc, RSH);

        // GEMM3: houtT[n][c] = attn[n][:] . v[c][:]   (K = 1024)
        gemm128<3><<<dim3(8, 4, nb), dim3(256), 0, stream>>>(
            sc, RSH, N_,  vbuf, RSH, N_,
            houtT, RSH, C_,  nullptr, nullptr, 0, N_, 0.f);

        // GEMM4: out[o][n] = pw[o][:] . houtT[n][:] + pb[o] + x[o][n]
        gemm128<4><<<dim3(4, 8, nb), dim3(256), 0, stream>>>(
            wproj, 0, C_,  houtT, RSH, C_,
            out + (size_t)b0 * C_ * N_, (long)C_ * N_, N_,
            proj_b, x + (size_t)b0 * C_ * N_, (long)C_ * N_, C_, 0.f);
    }
}

// Round 8
// 429.023 us; speedup vs baseline: 6.6101x; 1.0135x over previous
//
#include <hip/hip_runtime.h>
#include <math.h>

// Problem constants
#define B_ 32
#define C_ 512
#define G_ 32
#define N_ 1024          // H*W
#define OC3_ 1536        // 3*C
#define EPS_ 1e-5f

typedef __attribute__((ext_vector_type(8))) short short8;
typedef __attribute__((ext_vector_type(4))) float f32x4;

// fp32 -> bf16 RNE
__device__ inline unsigned short f2bf(float f) {
    unsigned u = __builtin_bit_cast(unsigned, f);
    u += 0x7fffu + ((u >> 16) & 1u);
    return (unsigned short)(u >> 16);
}
__device__ inline unsigned pack2(float lo, float hi) {
    return (unsigned)f2bf(lo) | ((unsigned)f2bf(hi) << 16);
}
__device__ inline float bf2f(unsigned short u) {
    return __builtin_bit_cast(float, ((unsigned)u) << 16);
}

// async global->LDS 16 B per lane (gfx950). LDS dest = wave-uniform base +
// lane*16; all call sites use &lds[tid*8] (shorts). Row stride stays an
// unpadded 32 shorts; frag-read bank conflicts handled by XOR chunk swizzle.
typedef const __attribute__((address_space(1))) unsigned int* gas_u32;
typedef __attribute__((address_space(3))) unsigned int* las_u32;
__device__ __forceinline__ void cp16(unsigned short* lds, const unsigned short* g) {
    __builtin_amdgcn_global_load_lds((gas_u32)g, (las_u32)lds, 16, 0, 0);
}

// ---------------------------------------------------------------------------
// GroupNorm statistics. One block per (b,g): 16 ch x 1024 = 16384 floats.
// ---------------------------------------------------------------------------
__global__ __launch_bounds__(256) void gn_stats_kernel(
    const float* __restrict__ x, float* __restrict__ stats)
{
    int bg = blockIdx.x;
    const float4* xv = (const float4*)(x + (size_t)bg * 16 * N_);
    float s = 0.f, ss = 0.f;
    for (int i = threadIdx.x; i < 4096; i += 256) {
        float4 v = xv[i];
        s  += v.x + v.y + v.z + v.w;
        ss += v.x*v.x + v.y*v.y + v.z*v.z + v.w*v.w;
    }
    __shared__ float r1[256], r2[256];
    r1[threadIdx.x] = s; r2[threadIdx.x] = ss;
    __syncthreads();
    for (int off = 128; off > 0; off >>= 1) {
        if (threadIdx.x < off) {
            r1[threadIdx.x] += r1[threadIdx.x + off];
            r2[threadIdx.x] += r2[threadIdx.x + off];
        }
        __syncthreads();
    }
    if (threadIdx.x == 0) {
        float mean = r1[0] * (1.f / 16384.f);
        float var  = r2[0] * (1.f / 16384.f) - mean * mean;
        stats[bg * 2 + 0] = mean;
        stats[bg * 2 + 1] = rsqrtf(var + EPS_);
    }
}

// ---------------------------------------------------------------------------
// fp32 -> bf16 elementwise convert (weights; once per launch).
// ---------------------------------------------------------------------------
__global__ __launch_bounds__(256) void cvt_bf16_kernel(
    const float* __restrict__ src, unsigned short* __restrict__ dst, int n4)
{
    int i = blockIdx.x * 256 + threadIdx.x;
    if (i >= n4) return;
    float4 v = ((const float4*)src)[i];
    uint2 o; o.x = pack2(v.x, v.y); o.y = pack2(v.z, v.w);
    ((uint2*)dst)[i] = o;
}

// ---------------------------------------------------------------------------
// hhatT producer: x[b][c][n] fp32 (coalesced reads) -> GN affine ->
// hhatT[bz][n][c] bf16 via 64x64 LDS tile transpose.
// ---------------------------------------------------------------------------
__global__ __launch_bounds__(256) void hhatT_kernel(
    const float* __restrict__ x, const float* __restrict__ stats,
    const float* __restrict__ nw, const float* __restrict__ nbias,
    unsigned short* __restrict__ hhatT, long sH, int b0)
{
    int bz = blockIdx.z, b = b0 + bz;
    int nt = blockIdx.x * 64, ct = blockIdx.y * 64;
    const float* xb = x + (size_t)b * C_ * N_;
    const float* st = stats + b * 2 * G_;

    __shared__ float T[64][65];
    int tid = threadIdx.x;

    #pragma unroll
    for (int p = 0; p < 4; ++p) {
        int c = p * 16 + (tid >> 4);
        int n4 = (tid & 15) * 4;
        float4 v = *(const float4*)&xb[(size_t)(ct + c) * N_ + nt + n4];
        int g = (ct + c) >> 4;
        float w0 = nw[ct + c] * st[g * 2 + 1];
        float bb = nbias[ct + c] - st[g * 2] * w0;
        T[c][n4]   = v.x * w0 + bb;
        T[c][n4+1] = v.y * w0 + bb;
        T[c][n4+2] = v.z * w0 + bb;
        T[c][n4+3] = v.w * w0 + bb;
    }
    __syncthreads();
    #pragma unroll
    for (int p = 0; p < 2; ++p) {
        int n  = p * 32 + (tid >> 3);
        int c8 = (tid & 7) * 8;
        short8 s;
        #pragma unroll
        for (int u = 0; u < 8; ++u) s[u] = (short)f2bf(T[c8 + u][n]);
        *(short8*)&hhatT[(size_t)bz * sH + (size_t)(nt + n) * C_ + ct + c8] = s;
    }
}

// ---------------------------------------------------------------------------
// 128x128 GEMM: D[row][col] = sum_k A[row][k] * B[col][k]  (+ epilogue)
// BK=32, 4 waves (2x2 of 64x64). DOUBLE-BUFFERED global_load_lds staging:
// at iter i the top barrier drains tile i's DMA (issued during iter i-1's
// compute), then tile i+1's DMA is issued into the other buffer before
// computing on tile i -- load latency overlaps the MFMA phase.
// XOR chunk swizzle keeps frag ds_read_b128 conflict-free (R7: conflicts=0).
// EPI: 0 bf16 +bias[col] | 1 bf16 +bias[row] | 2 bf16 *scale | 3 bf16
//      4 fp32 +bias[row]+aux (residual)
// ---------------------------------------------------------------------------
template<int EPI>
__global__ __launch_bounds__(256) void gemm128(
    const unsigned short* __restrict__ A, long sA, int lda,
    const unsigned short* __restrict__ B, long sB, int ldb,
    void* __restrict__ Dv, long sD, int ldd,
    const float* __restrict__ bias,
    const float* __restrict__ aux, long sAux,
    int K, float scale)
{
    int bz = blockIdx.z;
    const unsigned short* Ab = A + (size_t)bz * sA + (size_t)blockIdx.x * 128 * lda;
    const unsigned short* Bb = B + (size_t)bz * sB + (size_t)blockIdx.y * 128 * ldb;

    __shared__ __align__(16) unsigned short As[2][128 * 32];
    __shared__ __align__(16) unsigned short Bs[2][128 * 32];

    int tid = threadIdx.x;
    int w = tid >> 6, lane = tid & 63;
    int lm = lane & 15, q = lane >> 4;
    int wrow = (w >> 1) * 64, wcol = (w & 1) * 64;

    f32x4 acc[4][4];
    #pragma unroll
    for (int i = 0; i < 4; ++i)
        #pragma unroll
        for (int j = 0; j < 4; ++j) acc[i][j] = (f32x4)(0.f);

    int srow = tid >> 2;                              // staging row (0..63)
    int skc  = (((tid & 3) ^ ((tid >> 3) & 3))) * 8;  // swizzled global chunk
    int fco  = (q ^ ((lm >> 1) & 3)) * 8;             // frag physical chunk

    // per-thread staging source pointers (advance 32 shorts per tile)
    const unsigned short* a0p = Ab + (size_t)srow        * lda + skc;
    const unsigned short* a1p = Ab + (size_t)(64 + srow) * lda + skc;
    const unsigned short* b0p = Bb + (size_t)srow        * ldb + skc;
    const unsigned short* b1p = Bb + (size_t)(64 + srow) * ldb + skc;

    // prologue: stage tile 0 into buffer 0
    cp16(&As[0][tid * 8],        a0p);
    cp16(&As[0][2048 + tid * 8], a1p);
    cp16(&Bs[0][tid * 8],        b0p);
    cp16(&Bs[0][2048 + tid * 8], b1p);

    int nIter = K >> 5;
    for (int it = 0; it < nIter; ++it) {
        int cur = it & 1;
        __syncthreads();   // drains tile-it DMA (in flight since iter it-1)
        if (it + 1 < nIter) {
            int off = (it + 1) * 32;
            int nxt = cur ^ 1;
            cp16(&As[nxt][tid * 8],        a0p + off);
            cp16(&As[nxt][2048 + tid * 8], a1p + off);
            cp16(&Bs[nxt][tid * 8],        b0p + off);
            cp16(&Bs[nxt][2048 + tid * 8], b1p + off);
        }
        short8 af[4], bf[4];
        #pragma unroll
        for (int i = 0; i < 4; ++i)
            af[i] = *(const short8*)&As[cur][(wrow + i * 16 + lm) * 32 + fco];
        #pragma unroll
        for (int j = 0; j < 4; ++j)
            bf[j] = *(const short8*)&Bs[cur][(wcol + j * 16 + lm) * 32 + fco];
        #pragma unroll
        for (int i = 0; i < 4; ++i)
            #pragma unroll
            for (int j = 0; j < 4; ++j)
                acc[i][j] = __builtin_amdgcn_mfma_f32_16x16x32_bf16(
                    af[i], bf[j], acc[i][j], 0, 0, 0);
    }

    int grow = blockIdx.x * 128 + wrow;
    int gcol = blockIdx.y * 128 + wcol;

    #pragma unroll
    for (int j = 0; j < 4; ++j) {
        int col = gcol + j * 16 + lm;
        float cb = (EPI == 0) ? bias[col] : 0.f;
        #pragma unroll
        for (int i = 0; i < 4; ++i) {
            #pragma unroll
            for (int r = 0; r < 4; ++r) {
                int row = grow + i * 16 + q * 4 + r;
                float vle = acc[i][j][r];
                if constexpr (EPI == 0) {
                    vle += cb;
                    ((unsigned short*)Dv)[(size_t)bz * sD + (size_t)row * ldd + col] = f2bf(vle);
                } else if constexpr (EPI == 1) {
                    vle += bias[row];
                    ((unsigned short*)Dv)[(size_t)bz * sD + (size_t)row * ldd + col] = f2bf(vle);
                } else if constexpr (EPI == 2) {
                    ((unsigned short*)Dv)[(size_t)bz * sD + (size_t)row * ldd + col] = f2bf(vle * scale);
                } else if constexpr (EPI == 3) {
                    ((unsigned short*)Dv)[(size_t)bz * sD + (size_t)row * ldd + col] = f2bf(vle);
                } else {
                    vle += bias[row] + aux[(size_t)bz * sAux + (size_t)row * ldd + col];
                    ((float*)Dv)[(size_t)bz * sD + (size_t)row * ldd + col] = vle;
                }
            }
        }
    }
}

// ---------------------------------------------------------------------------
// Softmax: in-place on bf16 scores. One WAVE per row (16 elems/lane),
// shuffle reductions, no barriers. Block = 4 waves = 4 rows.
// ---------------------------------------------------------------------------
__global__ __launch_bounds__(256) void softmax_kernel(
    unsigned short* __restrict__ sc, long sSc)
{
    int bz = blockIdx.y;
    int row = blockIdx.x * 4 + (threadIdx.x >> 6);
    int lane = threadIdx.x & 63;
    unsigned short* p = sc + (size_t)bz * sSc + (size_t)row * N_ + lane * 16;

    short8 s0 = *(const short8*)p;
    short8 s1 = *(const short8*)(p + 8);
    float v[16];
    #pragma unroll
    for (int i = 0; i < 8; ++i) {
        v[i]     = bf2f((unsigned short)s0[i]);
        v[8 + i] = bf2f((unsigned short)s1[i]);
    }
    float m = v[0];
    #pragma unroll
    for (int i = 1; i < 16; ++i) m = fmaxf(m, v[i]);
    #pragma unroll
    for (int off = 32; off > 0; off >>= 1) m = fmaxf(m, __shfl_xor(m, off, 64));

    float sum = 0.f;
    #pragma unroll
    for (int i = 0; i < 16; ++i) { v[i] = __expf(v[i] - m); sum += v[i]; }
    #pragma unroll
    for (int off = 32; off > 0; off >>= 1) sum += __shfl_xor(sum, off, 64);
    float inv = 1.f / sum;

    short8 o0, o1;
    #pragma unroll
    for (int i = 0; i < 8; ++i) {
        o0[i] = (short)f2bf(v[i] * inv);
        o1[i] = (short)f2bf(v[8 + i] * inv);
    }
    *(short8*)p = o0;
    *(short8*)(p + 8) = o1;
}

// ---------------------------------------------------------------------------
extern "C" void kernel_launch(void* const* d_in, const int* in_sizes, int n_in,
                              void* d_out, int out_size, void* d_ws, size_t ws_size,
                              hipStream_t stream) {
    const float* x      = (const float*)d_in[0];
    const float* norm_w = (const float*)d_in[1];
    const float* norm_b = (const float*)d_in[2];
    const float* qkv_w  = (const float*)d_in[3];
    const float* qkv_b  = (const float*)d_in[4];
    const float* proj_w = (const float*)d_in[5];
    const float* proj_b = (const float*)d_in[6];
    float* out = (float*)d_out;

    // Fixed region: stats (8 KB) + bf16 weights (2 MB).
    char* ws = (char*)d_ws;
    float* stats = (float*)ws;
    unsigned short* wqkv  = (unsigned short*)(ws + 8192);   // 1536x512
    unsigned short* wproj = wqkv + (size_t)OC3_ * C_;       // 512x512
    char* base = (char*)(wproj + (size_t)C_ * C_);
    const size_t fixed = 8192 + (size_t)OC3_ * C_ * 2 + (size_t)C_ * C_ * 2;

    // Per-batch aliased region: 6 MB.
    //   [0,2M)  qkT bf16 [n][1024]
    //   [2,3M)  v bf16 [c][n]
    //   [3,4M)  hhatT bf16 [n][c]  -> after GEMM2 reused as houtT bf16 [n][c]
    //   [4,6M)  sc bf16 [n][m]     -> softmax in-place -> attn
    const size_t REG = 6u << 20;
    const long RSH = (long)(REG / 2);         // region stride in shorts

    size_t avail = ws_size > fixed ? ws_size - fixed : 0;
    int chunk = (int)(avail / REG);
    if (chunk < 1) chunk = 1;
    if (chunk > B_) chunk = B_;

    gn_stats_kernel<<<dim3(B_ * G_), dim3(256), 0, stream>>>(x, stats);
    cvt_bf16_kernel<<<dim3((OC3_ * C_ / 4 + 255) / 256), dim3(256), 0, stream>>>(
        qkv_w, wqkv, OC3_ * C_ / 4);
    cvt_bf16_kernel<<<dim3((C_ * C_ / 4 + 255) / 256), dim3(256), 0, stream>>>(
        proj_w, wproj, C_ * C_ / 4);

    const float scale = 0.044194173824159216f;  // 512^-0.5

    unsigned short* qkT   = (unsigned short*)base;
    unsigned short* vbuf  = (unsigned short*)(base + (2u << 20));
    unsigned short* hhatT = (unsigned short*)(base + (3u << 20));
    unsigned short* houtT = (unsigned short*)(base + (3u << 20)); // aliases hhatT
    unsigned short* sc    = (unsigned short*)(base + (4u << 20)); // scores/attn

    for (int b0 = 0; b0 < B_; b0 += chunk) {
        int nb = B_ - b0 < chunk ? B_ - b0 : chunk;

        hhatT_kernel<<<dim3(N_/64, C_/64, nb), dim3(256), 0, stream>>>(
            x, stats, norm_w, norm_b, hhatT, RSH, b0);

        // GEMM1a: qkT[n][o] = hhatT[n][:] . Wqk[o][:]   (o in [0,1024))
        gemm128<0><<<dim3(8, 8, nb), dim3(256), 0, stream>>>(
            hhatT, RSH, C_,  wqkv, 0, C_,
            qkT, RSH, 1024,  qkv_b, nullptr, 0, C_, 0.f);

        // GEMM1b: v[c][n] = Wv[c][:] . hhatT[n][:]
        gemm128<1><<<dim3(4, 8, nb), dim3(256), 0, stream>>>(
            wqkv + (size_t)1024 * C_, 0, C_,  hhatT, RSH, C_,
            vbuf, RSH, N_,  qkv_b + 1024, nullptr, 0, C_, 0.f);

        // GEMM2: sc[n][m] = bf16( scale * qkT[n][0:512] . qkT[m][512:1024] )
        gemm128<2><<<dim3(8, 8, nb), dim3(256), 0, stream>>>(
            qkT, RSH, 1024,  qkT + 512, RSH, 1024,
            sc, RSH, N_,  nullptr, nullptr, 0, C_, scale);

        softmax_kernel<<<dim3(N_/4, nb), dim3(256), 0, stream>>>(sc, RSH);

        // GEMM3: houtT[n][c] = attn[n][:] . v[c][:]   (K = 1024)
        gemm128<3><<<dim3(8, 4, nb), dim3(256), 0, stream>>>(
            sc, RSH, N_,  vbuf, RSH, N_,
            houtT, RSH, C_,  nullptr, nullptr, 0, N_, 0.f);

        // GEMM4: out[o][n] = pw[o][:] . houtT[n][:] + pb[o] + x[o][n]
        gemm128<4><<<dim3(4, 8, nb), dim3(256), 0, stream>>>(
            wproj, 0, C_,  houtT, RSH, C_,
            out + (size_t)b0 * C_ * N_, (long)C_ * N_, N_,
            proj_b, x + (size_t)b0 * C_ * N_, (long)C_ * N_, C_, 0.f);
    }
}

// Round 9
// 408.369 us; speedup vs baseline: 6.9444x; 1.0506x over previous
//
#include <hip/hip_runtime.h>
#include <math.h>

// Problem constants
#define B_ 32
#define C_ 512
#define G_ 32
#define N_ 1024          // H*W
#define OC3_ 1536        // 3*C
#define EPS_ 1e-5f

typedef __attribute__((ext_vector_type(8))) short short8;
typedef __attribute__((ext_vector_type(4))) float f32x4;

// fp32 -> bf16 RNE
__device__ inline unsigned short f2bf(float f) {
    unsigned u = __builtin_bit_cast(unsigned, f);
    u += 0x7fffu + ((u >> 16) & 1u);
    return (unsigned short)(u >> 16);
}
__device__ inline unsigned pack2(float lo, float hi) {
    return (unsigned)f2bf(lo) | ((unsigned)f2bf(hi) << 16);
}
__device__ inline float bf2f(unsigned short u) {
    return __builtin_bit_cast(float, ((unsigned)u) << 16);
}

// async global->LDS 16 B per lane (gfx950). LDS dest = wave-uniform base +
// lane*16; all call sites use &lds[tid*8] (shorts). Row stride stays an
// unpadded 32 shorts; frag-read bank conflicts handled by XOR chunk swizzle.
typedef const __attribute__((address_space(1))) unsigned int* gas_u32;
typedef __attribute__((address_space(3))) unsigned int* las_u32;
__device__ __forceinline__ void cp16(unsigned short* lds, const unsigned short* g) {
    __builtin_amdgcn_global_load_lds((gas_u32)g, (las_u32)lds, 16, 0, 0);
}

// ---------------------------------------------------------------------------
// GroupNorm statistics. One block per (b,g): 16 ch x 1024 = 16384 floats.
// ---------------------------------------------------------------------------
__global__ __launch_bounds__(256) void gn_stats_kernel(
    const float* __restrict__ x, float* __restrict__ stats)
{
    int bg = blockIdx.x;
    const float4* xv = (const float4*)(x + (size_t)bg * 16 * N_);
    float s = 0.f, ss = 0.f;
    for (int i = threadIdx.x; i < 4096; i += 256) {
        float4 v = xv[i];
        s  += v.x + v.y + v.z + v.w;
        ss += v.x*v.x + v.y*v.y + v.z*v.z + v.w*v.w;
    }
    __shared__ float r1[256], r2[256];
    r1[threadIdx.x] = s; r2[threadIdx.x] = ss;
    __syncthreads();
    for (int off = 128; off > 0; off >>= 1) {
        if (threadIdx.x < off) {
            r1[threadIdx.x] += r1[threadIdx.x + off];
            r2[threadIdx.x] += r2[threadIdx.x + off];
        }
        __syncthreads();
    }
    if (threadIdx.x == 0) {
        float mean = r1[0] * (1.f / 16384.f);
        float var  = r2[0] * (1.f / 16384.f) - mean * mean;
        stats[bg * 2 + 0] = mean;
        stats[bg * 2 + 1] = rsqrtf(var + EPS_);
    }
}

// ---------------------------------------------------------------------------
// fp32 -> bf16 elementwise convert (weights; once per launch).
// ---------------------------------------------------------------------------
__global__ __launch_bounds__(256) void cvt_bf16_kernel(
    const float* __restrict__ src, unsigned short* __restrict__ dst, int n4)
{
    int i = blockIdx.x * 256 + threadIdx.x;
    if (i >= n4) return;
    float4 v = ((const float4*)src)[i];
    uint2 o; o.x = pack2(v.x, v.y); o.y = pack2(v.z, v.w);
    ((uint2*)dst)[i] = o;
}

// ---------------------------------------------------------------------------
// hhatT producer: x[b][c][n] fp32 (coalesced reads) -> GN affine ->
// hhatT[bz][n][c] bf16 via 64x64 LDS tile transpose.
// ---------------------------------------------------------------------------
__global__ __launch_bounds__(256) void hhatT_kernel(
    const float* __restrict__ x, const float* __restrict__ stats,
    const float* __restrict__ nw, const float* __restrict__ nbias,
    unsigned short* __restrict__ hhatT, long sH, int b0)
{
    int bz = blockIdx.z, b = b0 + bz;
    int nt = blockIdx.x * 64, ct = blockIdx.y * 64;
    const float* xb = x + (size_t)b * C_ * N_;
    const float* st = stats + b * 2 * G_;

    __shared__ float T[64][65];
    int tid = threadIdx.x;

    #pragma unroll
    for (int p = 0; p < 4; ++p) {
        int c = p * 16 + (tid >> 4);
        int n4 = (tid & 15) * 4;
        float4 v = *(const float4*)&xb[(size_t)(ct + c) * N_ + nt + n4];
        int g = (ct + c) >> 4;
        float w0 = nw[ct + c] * st[g * 2 + 1];
        float bb = nbias[ct + c] - st[g * 2] * w0;
        T[c][n4]   = v.x * w0 + bb;
        T[c][n4+1] = v.y * w0 + bb;
        T[c][n4+2] = v.z * w0 + bb;
        T[c][n4+3] = v.w * w0 + bb;
    }
    __syncthreads();
    #pragma unroll
    for (int p = 0; p < 2; ++p) {
        int n  = p * 32 + (tid >> 3);
        int c8 = (tid & 7) * 8;
        short8 s;
        #pragma unroll
        for (int u = 0; u < 8; ++u) s[u] = (short)f2bf(T[c8 + u][n]);
        *(short8*)&hhatT[(size_t)bz * sH + (size_t)(nt + n) * C_ + ct + c8] = s;
    }
}

// ---------------------------------------------------------------------------
// 128x128 GEMM: D[row][col] = sum_k A[row][k] * B[col][k]  (+ epilogue)
// BK=32, 4 waves (2x2 of 64x64). Double-buffered global_load_lds staging
// (cross-iteration prefetch) + XOR chunk swizzle (R7: conflicts=0).
// XCD-LOCALITY SWIZZLE (R9): 1-D grid; when nbz%8==0, block ids are laid out
// so bid%8 == batch%8 -- with the hardware's round-robin bid->XCD mapping,
// each batch's blocks (and its <=3 MB A/B working set) stay on ONE XCD's
// 4 MB L2, turning the exposed ~900-cyc HBM misses into ~200-cyc L2 hits.
// EPI: 0 bf16 +bias[col] | 1 bf16 +bias[row] | 2 bf16 *scale | 3 bf16
//      4 fp32 +bias[row]+aux (residual)
// ---------------------------------------------------------------------------
template<int EPI>
__global__ __launch_bounds__(256) void gemm128(
    const unsigned short* __restrict__ A, long sA, int lda,
    const unsigned short* __restrict__ B, long sB, int ldb,
    void* __restrict__ Dv, long sD, int ldd,
    const float* __restrict__ bias,
    const float* __restrict__ aux, long sAux,
    int K, float scale, int gx, int gy, int nbz)
{
    int bid = blockIdx.x;
    int nbpb = gx * gy;
    int bx, by, bz;
    if ((nbz & 7) == 0) {
        int xcd = bid & 7;
        int rest = bid >> 3;
        int local = rest % nbpb;
        int bg = rest / nbpb;
        bz = bg * 8 + xcd;
        bx = local % gx;
        by = local / gx;
    } else {
        bz = bid / nbpb;
        int local = bid % nbpb;
        bx = local % gx;
        by = local / gx;
    }

    const unsigned short* Ab = A + (size_t)bz * sA + (size_t)bx * 128 * lda;
    const unsigned short* Bb = B + (size_t)bz * sB + (size_t)by * 128 * ldb;

    __shared__ __align__(16) unsigned short As[2][128 * 32];
    __shared__ __align__(16) unsigned short Bs[2][128 * 32];

    int tid = threadIdx.x;
    int w = tid >> 6, lane = tid & 63;
    int lm = lane & 15, q = lane >> 4;
    int wrow = (w >> 1) * 64, wcol = (w & 1) * 64;

    f32x4 acc[4][4];
    #pragma unroll
    for (int i = 0; i < 4; ++i)
        #pragma unroll
        for (int j = 0; j < 4; ++j) acc[i][j] = (f32x4)(0.f);

    int srow = tid >> 2;                              // staging row (0..63)
    int skc  = (((tid & 3) ^ ((tid >> 3) & 3))) * 8;  // swizzled global chunk
    int fco  = (q ^ ((lm >> 1) & 3)) * 8;             // frag physical chunk

    const unsigned short* a0p = Ab + (size_t)srow        * lda + skc;
    const unsigned short* a1p = Ab + (size_t)(64 + srow) * lda + skc;
    const unsigned short* b0p = Bb + (size_t)srow        * ldb + skc;
    const unsigned short* b1p = Bb + (size_t)(64 + srow) * ldb + skc;

    // prologue: stage tile 0 into buffer 0
    cp16(&As[0][tid * 8],        a0p);
    cp16(&As[0][2048 + tid * 8], a1p);
    cp16(&Bs[0][tid * 8],        b0p);
    cp16(&Bs[0][2048 + tid * 8], b1p);

    int nIter = K >> 5;
    for (int it = 0; it < nIter; ++it) {
        int cur = it & 1;
        __syncthreads();   // drains tile-it DMA (in flight since iter it-1)
        if (it + 1 < nIter) {
            int off = (it + 1) * 32;
            int nxt = cur ^ 1;
            cp16(&As[nxt][tid * 8],        a0p + off);
            cp16(&As[nxt][2048 + tid * 8], a1p + off);
            cp16(&Bs[nxt][tid * 8],        b0p + off);
            cp16(&Bs[nxt][2048 + tid * 8], b1p + off);
        }
        short8 af[4], bf[4];
        #pragma unroll
        for (int i = 0; i < 4; ++i)
            af[i] = *(const short8*)&As[cur][(wrow + i * 16 + lm) * 32 + fco];
        #pragma unroll
        for (int j = 0; j < 4; ++j)
            bf[j] = *(const short8*)&Bs[cur][(wcol + j * 16 + lm) * 32 + fco];
        #pragma unroll
        for (int i = 0; i < 4; ++i)
            #pragma unroll
            for (int j = 0; j < 4; ++j)
                acc[i][j] = __builtin_amdgcn_mfma_f32_16x16x32_bf16(
                    af[i], bf[j], acc[i][j], 0, 0, 0);
    }

    int grow = bx * 128 + wrow;
    int gcol = by * 128 + wcol;

    #pragma unroll
    for (int j = 0; j < 4; ++j) {
        int col = gcol + j * 16 + lm;
        float cb = (EPI == 0) ? bias[col] : 0.f;
        #pragma unroll
        for (int i = 0; i < 4; ++i) {
            #pragma unroll
            for (int r = 0; r < 4; ++r) {
                int row = grow + i * 16 + q * 4 + r;
                float vle = acc[i][j][r];
                if constexpr (EPI == 0) {
                    vle += cb;
                    ((unsigned short*)Dv)[(size_t)bz * sD + (size_t)row * ldd + col] = f2bf(vle);
                } else if constexpr (EPI == 1) {
                    vle += bias[row];
                    ((unsigned short*)Dv)[(size_t)bz * sD + (size_t)row * ldd + col] = f2bf(vle);
                } else if constexpr (EPI == 2) {
                    ((unsigned short*)Dv)[(size_t)bz * sD + (size_t)row * ldd + col] = f2bf(vle * scale);
                } else if constexpr (EPI == 3) {
                    ((unsigned short*)Dv)[(size_t)bz * sD + (size_t)row * ldd + col] = f2bf(vle);
                } else {
                    vle += bias[row] + aux[(size_t)bz * sAux + (size_t)row * ldd + col];
                    ((float*)Dv)[(size_t)bz * sD + (size_t)row * ldd + col] = vle;
                }
            }
        }
    }
}

// ---------------------------------------------------------------------------
// Softmax: in-place on bf16 scores. One WAVE per row (16 elems/lane),
// shuffle reductions, no barriers. Block = 4 waves = 4 rows.
// ---------------------------------------------------------------------------
__global__ __launch_bounds__(256) void softmax_kernel(
    unsigned short* __restrict__ sc, long sSc)
{
    int bz = blockIdx.y;
    int row = blockIdx.x * 4 + (threadIdx.x >> 6);
    int lane = threadIdx.x & 63;
    unsigned short* p = sc + (size_t)bz * sSc + (size_t)row * N_ + lane * 16;

    short8 s0 = *(const short8*)p;
    short8 s1 = *(const short8*)(p + 8);
    float v[16];
    #pragma unroll
    for (int i = 0; i < 8; ++i) {
        v[i]     = bf2f((unsigned short)s0[i]);
        v[8 + i] = bf2f((unsigned short)s1[i]);
    }
    float m = v[0];
    #pragma unroll
    for (int i = 1; i < 16; ++i) m = fmaxf(m, v[i]);
    #pragma unroll
    for (int off = 32; off > 0; off >>= 1) m = fmaxf(m, __shfl_xor(m, off, 64));

    float sum = 0.f;
    #pragma unroll
    for (int i = 0; i < 16; ++i) { v[i] = __expf(v[i] - m); sum += v[i]; }
    #pragma unroll
    for (int off = 32; off > 0; off >>= 1) sum += __shfl_xor(sum, off, 64);
    float inv = 1.f / sum;

    short8 o0, o1;
    #pragma unroll
    for (int i = 0; i < 8; ++i) {
        o0[i] = (short)f2bf(v[i] * inv);
        o1[i] = (short)f2bf(v[8 + i] * inv);
    }
    *(short8*)p = o0;
    *(short8*)(p + 8) = o1;
}

// ---------------------------------------------------------------------------
extern "C" void kernel_launch(void* const* d_in, const int* in_sizes, int n_in,
                              void* d_out, int out_size, void* d_ws, size_t ws_size,
                              hipStream_t stream) {
    const float* x      = (const float*)d_in[0];
    const float* norm_w = (const float*)d_in[1];
    const float* norm_b = (const float*)d_in[2];
    const float* qkv_w  = (const float*)d_in[3];
    const float* qkv_b  = (const float*)d_in[4];
    const float* proj_w = (const float*)d_in[5];
    const float* proj_b = (const float*)d_in[6];
    float* out = (float*)d_out;

    // Fixed region: stats (8 KB) + bf16 weights (2 MB).
    char* ws = (char*)d_ws;
    float* stats = (float*)ws;
    unsigned short* wqkv  = (unsigned short*)(ws + 8192);   // 1536x512
    unsigned short* wproj = wqkv + (size_t)OC3_ * C_;       // 512x512
    char* base = (char*)(wproj + (size_t)C_ * C_);
    const size_t fixed = 8192 + (size_t)OC3_ * C_ * 2 + (size_t)C_ * C_ * 2;

    // Per-batch aliased region: 6 MB.
    //   [0,2M)  qkT bf16 [n][1024]
    //   [2,3M)  v bf16 [c][n]
    //   [3,4M)  hhatT bf16 [n][c]  -> after GEMM2 reused as houtT bf16 [n][c]
    //   [4,6M)  sc bf16 [n][m]     -> softmax in-place -> attn
    const size_t REG = 6u << 20;
    const long RSH = (long)(REG / 2);         // region stride in shorts

    size_t avail = ws_size > fixed ? ws_size - fixed : 0;
    int chunk = (int)(avail / REG);
    if (chunk < 1) chunk = 1;
    if (chunk > B_) chunk = B_;

    gn_stats_kernel<<<dim3(B_ * G_), dim3(256), 0, stream>>>(x, stats);
    cvt_bf16_kernel<<<dim3((OC3_ * C_ / 4 + 255) / 256), dim3(256), 0, stream>>>(
        qkv_w, wqkv, OC3_ * C_ / 4);
    cvt_bf16_kernel<<<dim3((C_ * C_ / 4 + 255) / 256), dim3(256), 0, stream>>>(
        proj_w, wproj, C_ * C_ / 4);

    const float scale = 0.044194173824159216f;  // 512^-0.5

    unsigned short* qkT   = (unsigned short*)base;
    unsigned short* vbuf  = (unsigned short*)(base + (2u << 20));
    unsigned short* hhatT = (unsigned short*)(base + (3u << 20));
    unsigned short* houtT = (unsigned short*)(base + (3u << 20)); // aliases hhatT
    unsigned short* sc    = (unsigned short*)(base + (4u << 20)); // scores/attn

    for (int b0 = 0; b0 < B_; b0 += chunk) {
        int nb = B_ - b0 < chunk ? B_ - b0 : chunk;

        hhatT_kernel<<<dim3(N_/64, C_/64, nb), dim3(256), 0, stream>>>(
            x, stats, norm_w, norm_b, hhatT, RSH, b0);

        // GEMM1a: qkT[n][o] = hhatT[n][:] . Wqk[o][:]   (o in [0,1024))
        gemm128<0><<<dim3(8 * 8 * nb), dim3(256), 0, stream>>>(
            hhatT, RSH, C_,  wqkv, 0, C_,
            qkT, RSH, 1024,  qkv_b, nullptr, 0, C_, 0.f, 8, 8, nb);

        // GEMM1b: v[c][n] = Wv[c][:] . hhatT[n][:]
        gemm128<1><<<dim3(4 * 8 * nb), dim3(256), 0, stream>>>(
            wqkv + (size_t)1024 * C_, 0, C_,  hhatT, RSH, C_,
            vbuf, RSH, N_,  qkv_b + 1024, nullptr, 0, C_, 0.f, 4, 8, nb);

        // GEMM2: sc[n][m] = bf16( scale * qkT[n][0:512] . qkT[m][512:1024] )
        gemm128<2><<<dim3(8 * 8 * nb), dim3(256), 0, stream>>>(
            qkT, RSH, 1024,  qkT + 512, RSH, 1024,
            sc, RSH, N_,  nullptr, nullptr, 0, C_, scale, 8, 8, nb);

        softmax_kernel<<<dim3(N_/4, nb), dim3(256), 0, stream>>>(sc, RSH);

        // GEMM3: houtT[n][c] = attn[n][:] . v[c][:]   (K = 1024)
        gemm128<3><<<dim3(8 * 4 * nb), dim3(256), 0, stream>>>(
            sc, RSH, N_,  vbuf, RSH, N_,
            houtT, RSH, C_,  nullptr, nullptr, 0, N_, 0.f, 8, 4, nb);

        // GEMM4: out[o][n] = pw[o][:] . houtT[n][:] + pb[o] + x[o][n]
        gemm128<4><<<dim3(4 * 8 * nb), dim3(256), 0, stream>>>(
            wproj, 0, C_,  houtT, RSH, C_,
            out + (size_t)b0 * C_ * N_, (long)C_ * N_, N_,
            proj_b, x + (size_t)b0 * C_ * N_, (long)C_ * N_, C_, 0.f, 4, 8, nb);
    }
}